// Round 9
// baseline (1125.101 us; speedup 1.0000x reference)
//
#include <hip/hip_runtime.h>
#include <cstdint>
#include <cstddef>

#define DEV __device__ __forceinline__

typedef float f32x4 __attribute__((ext_vector_type(4)));
typedef short s16x8 __attribute__((ext_vector_type(8)));

DEV float gelu_f(float x) { return 0.5f * x * (1.0f + erff(x * 0.70710678118654752f)); }

DEV uint32_t fbits(float x) { return __builtin_bit_cast(uint32_t, x); }

// round-to-nearest-even bf16
DEV uint16_t bf16_rne(float x) {
    uint32_t u = fbits(x);
    return (uint16_t)((u + 0x7FFFu + ((u >> 16) & 1u)) >> 16);
}

DEV void gload16(const void* g, void* l) {
    __builtin_amdgcn_global_load_lds(
        (const __attribute__((address_space(1))) uint32_t*)g,
        (__attribute__((address_space(3))) uint32_t*)l, 16, 0, 0);
}

// ---------------------------------------------------------------------------
// 1-pass bf16 MFMA GEMM.  A [M][K] bf16 (RNE), B [N][K] bf16 (RNE, k-major).
// C = A@B^T, fp32 accumulate.  2-phase double-buffered global_load_lds
// pipeline; XCD-aware block swizzle.  LDS capped at 2*HALF (32 KB @128^2,
// ~4 blocks/CU); epilogue bounces acc through LDS in 32-row chunks so global
// stores stay coalesced without inflating LDS.
// ---------------------------------------------------------------------------
template<int BM, int BN, bool BIAS, bool GELU, bool RES, bool POS,
         bool OUTF32, bool OUTB16>
__global__ __launch_bounds__(256)
void mfma_gemm(const uint16_t* __restrict__ Ah, const uint16_t* __restrict__ Bh,
               float* __restrict__ C, uint16_t* __restrict__ Cb,
               const float* __restrict__ bias, const float* __restrict__ res,
               const float* __restrict__ pos, int M, int N, int K)
{
    constexpr int WTM = BM / 2, WTN = BN / 2;
    constexpr int FM = WTM / 16, FN = WTN / 16;
    constexpr int NA = BM / 16, NB = BN / 16;      // 1KB chunks per plane
    constexpr int TI = NA + NB;                    // gloads per K-step
    constexpr int TI4 = TI / 4;                    // per wave
    constexpr int HALF = (BM + BN) * 64;           // bytes per K-step
    constexpr int BNP = BN + 4;
    constexpr int CR  = 32;                        // epilogue chunk rows
    constexpr int NCH = BM / CR;
    static_assert(CR * BNP * 4 <= 2 * HALF, "chunk must fit LDS");

    __shared__ __align__(16) uint8_t smem[2 * HALF];
    constexpr int offB = BM * 64;

    const int tid = threadIdx.x;
    const int w = tid >> 6, l = tid & 63;
    const int wr = w >> 1, wc = w & 1;

    // XCD-aware bijective swizzle (all grids here are %8 == 0)
    const int gx = gridDim.x;
    const int nwg = gx * gridDim.y;
    const int lin = blockIdx.y * gx + blockIdx.x;
    const int cpx = nwg >> 3;
    const int swz = (lin & 7) * cpx + (lin >> 3);
    const int bxs = swz % gx, bys = swz / gx;
    const int bm0 = bys * BM, bn0 = bxs * BN;
    const size_t sK = (size_t)K * 2;

    const int srow  = l >> 2;
    const int sslot = (l & 3) ^ ((l >> 3) & 3);
    const uint8_t* gsrc[TI4];
    uint32_t loff[TI4];
#pragma unroll
    for (int j = 0; j < TI4; ++j) {
        int f = w * TI4 + j;
        int p = (f < NA) ? 0 : 1;
        int c = p ? (f - NA) : f;
        const uint16_t* base = p ? Bh : Ah;
        int rb = p ? bn0 : bm0;
        gsrc[j] = (const uint8_t*)base + (size_t)(rb + c * 16 + srow) * sK + sslot * 16;
        loff[j] = (uint32_t)((p ? offB : 0) + c * 1024);
    }

    const int lr = l & 15;
    const int sl16 = ((l >> 4) ^ ((lr >> 1) & 3)) * 16;
    const int aofs = (wr * WTM + lr) * 64 + sl16;
    const int bofs = (wc * WTN + lr) * 64 + sl16;

    f32x4 acc[FM][FN];
#pragma unroll
    for (int m = 0; m < FM; ++m)
#pragma unroll
        for (int n = 0; n < FN; ++n) acc[m][n] = (f32x4){0.f, 0.f, 0.f, 0.f};

    {
        const uint8_t* s0 = smem;
#pragma unroll
        for (int j = 0; j < TI4; ++j)
            gload16(gsrc[j], (void*)(s0 + loff[j]));
    }
    asm volatile("s_waitcnt vmcnt(0)" ::: "memory");
    __builtin_amdgcn_s_barrier();

    int cur = 0;
    for (int k0 = 0; k0 < K; k0 += 32) {
        const bool more = (k0 + 32 < K);
        if (more) {
            const size_t kb = (size_t)(k0 + 32) * 2;
            uint8_t* dst = smem + (cur ^ 1) * HALF;
#pragma unroll
            for (int j = 0; j < TI4; ++j)
                gload16(gsrc[j] + kb, dst + loff[j]);
        }
        const uint8_t* sb = smem + cur * HALF;
        s16x8 af[FM], bf[FN];
#pragma unroll
        for (int m = 0; m < FM; ++m)
            af[m] = *(const s16x8*)(sb + aofs + m * 1024);
#pragma unroll
        for (int n = 0; n < FN; ++n)
            bf[n] = *(const s16x8*)(sb + offB + bofs + n * 1024);
#pragma unroll
        for (int m = 0; m < FM; ++m)
#pragma unroll
            for (int n = 0; n < FN; ++n)
                acc[m][n] = __builtin_amdgcn_mfma_f32_16x16x32_bf16(af[m], bf[n], acc[m][n], 0, 0, 0);

        if (more) {
            asm volatile("s_waitcnt vmcnt(0)" ::: "memory");
            __builtin_amdgcn_s_barrier();
        }
        cur ^= 1;
    }

    // ---- epilogue: chunked LDS bounce (CR rows/pass, LDS stays 2*HALF) ----
    float* lf = (float*)smem;
    const int r4 = (l >> 4) * 4;

    constexpr int C4PR = BN / 4;
    constexpr int RPP  = 256 / C4PR;
    const int rr = tid / C4PR, c4 = tid % C4PR;
    const int nn = bn0 + c4 * 4;

    float4 bv = {0.f, 0.f, 0.f, 0.f};
    if (BIAS) bv = *(const float4*)(bias + nn);

#pragma unroll
    for (int c = 0; c < NCH; ++c) {
        __syncthreads();   // prev chunk stores / K-loop reads done
        if (wr == (c * CR) / WTM) {
            const int mlo = ((c * CR) % WTM) / 16;
#pragma unroll
            for (int mi = 0; mi < CR / 16; ++mi) {
                int m = mlo + mi;
#pragma unroll
                for (int n = 0; n < FN; ++n) {
                    int col = wc * WTN + n * 16 + lr;
#pragma unroll
                    for (int r = 0; r < 4; ++r) {
                        int lrow = mi * 16 + r4 + r;
                        lf[lrow * BNP + col] = acc[m][n][r];
                    }
                }
            }
        }
        __syncthreads();
#pragma unroll
        for (int p = 0; p < CR / RPP; ++p) {
            int row = p * RPP + rr;
            int mm = bm0 + c * CR + row;
            float4 v = *(const float4*)&lf[row * BNP + c4 * 4];
            float* vp = &v.x;
            const float* bp = &bv.x;
#pragma unroll
            for (int q = 0; q < 4; ++q) {
                float x = vp[q];
                if (BIAS) x += bp[q];
                if (GELU) x = gelu_f(x);
                vp[q] = x;
            }
            if (RES) {
                float4 rv = *(const float4*)(res + (size_t)mm * N + nn);
                v.x += rv.x; v.y += rv.y; v.z += rv.z; v.w += rv.w;
            }
            if (POS) {
                float4 pv = *(const float4*)(pos + (size_t)(mm & 255) * N + nn);
                v.x += pv.x; v.y += pv.y; v.z += pv.z; v.w += pv.w;
            }
            size_t o = (size_t)mm * N + nn;
            if (OUTF32) *(float4*)(C + o) = v;
            if (OUTB16) {
                ushort4 hh;
                hh.x = bf16_rne(v.x); hh.y = bf16_rne(v.y);
                hh.z = bf16_rne(v.z); hh.w = bf16_rne(v.w);
                *(ushort4*)(Cb + o) = hh;
            }
        }
    }
}

// ---------------------------------------------------------------------------
// MFMA flash-style attention over RNE-bf16 QKV [8192][1536] u16.
// One block per (b,h); 4 waves x 64 queries.  Q held in REGISTERS (loaded
// once per-lane; fragments are lane-private).  K/V staged in padded LDS.
// LDS = 54 KB -> 2 blocks/CU.  Softmax fp32, no max-subtraction.
// ---------------------------------------------------------------------------
__global__ __launch_bounds__(256)
void mfma_attn(const uint16_t* __restrict__ QKVb, uint16_t* __restrict__ Oh)
{
    __shared__ __align__(16) uint8_t lds[55296];
    uint8_t* Ks = lds;              // [64][144B]
    uint8_t* Vt = lds + 9216;       // [64][144B]   (rows = d, cols = k)
    uint8_t* Ps = lds + 18432;      // [256][144B]

    const int tid = threadIdx.x;
    const int w = tid >> 6, l = tid & 63;
    const int lr = l & 15, lg = l >> 4;
    const int bh = blockIdx.x;
    const int b = bh >> 3, h = bh & 7;
    const uint16_t* base = QKVb + (size_t)b * 256 * 1536 + h * 64;
    const int q0 = w * 64;

    // ---- Q fragments direct to registers (lane-private, reused all kt) ----
    s16x8 qreg[2][4];
#pragma unroll
    for (int ks = 0; ks < 2; ++ks)
#pragma unroll
        for (int m = 0; m < 4; ++m)
            qreg[ks][m] = *(const s16x8*)(base + (size_t)(q0 + m * 16 + lr) * 1536 + ks * 32 + lg * 8);

    f32x4 oacc[4][4];
    float lrun[4][4];
#pragma unroll
    for (int m = 0; m < 4; ++m)
#pragma unroll
        for (int n = 0; n < 4; ++n) { oacc[m][n] = (f32x4){0.f,0.f,0.f,0.f}; lrun[m][n] = 0.f; }

    for (int kt = 0; kt < 4; ++kt) {
        __syncthreads();   // prev tile reads done
        {
            int r = tid >> 2, sp = (tid & 3) * 2;
            const uint16_t* kp = base + (size_t)(kt * 64 + r) * 1536 + 512;
#pragma unroll
            for (int ss = 0; ss < 2; ++ss) {
                int s = sp + ss;
                *(s16x8*)(Ks + r * 144 + s * 16) = *(const s16x8*)(kp + s * 8);
            }
        }
        {
            int k = tid & 63, d0 = (tid >> 6) * 16;
            const uint16_t* vp = base + (size_t)(kt * 64 + k) * 1536 + 1024 + d0;
            s16x8 a = *(const s16x8*)(vp);
            s16x8 c = *(const s16x8*)(vp + 8);
#pragma unroll
            for (int i = 0; i < 8; ++i) {
                *(uint16_t*)(Vt + (d0 + i) * 144 + k * 2)     = (uint16_t)a[i];
                *(uint16_t*)(Vt + (d0 + 8 + i) * 144 + k * 2) = (uint16_t)c[i];
            }
        }
        __syncthreads();   // staging visible

        // ---- S = Q K^T ----
        f32x4 sacc[4][4];
#pragma unroll
        for (int m = 0; m < 4; ++m)
#pragma unroll
            for (int n = 0; n < 4; ++n) sacc[m][n] = (f32x4){0.f,0.f,0.f,0.f};
#pragma unroll
        for (int ks = 0; ks < 2; ++ks) {
            s16x8 kf[4];
#pragma unroll
            for (int n = 0; n < 4; ++n)
                kf[n] = *(const s16x8*)(Ks + (n * 16 + lr) * 144 + ks * 64 + lg * 16);
#pragma unroll
            for (int m = 0; m < 4; ++m)
#pragma unroll
                for (int n = 0; n < 4; ++n)
                    sacc[m][n] = __builtin_amdgcn_mfma_f32_16x16x32_bf16(qreg[ks][m], kf[n], sacc[m][n], 0, 0, 0);
        }

        // ---- exp + P write + denominator ----
        float dp[4][4];
#pragma unroll
        for (int m = 0; m < 4; ++m)
#pragma unroll
            for (int r = 0; r < 4; ++r) dp[m][r] = 0.f;
#pragma unroll
        for (int m = 0; m < 4; ++m) {
#pragma unroll
            for (int n = 0; n < 4; ++n) {
#pragma unroll
                for (int r = 0; r < 4; ++r) {
                    float e = __expf(sacc[m][n][r] * 0.125f);
                    dp[m][r] += e;
                    int q = q0 + m * 16 + lg * 4 + r;
                    int k = n * 16 + lr;
                    *(uint16_t*)(Ps + q * 144 + k * 2) = bf16_rne(e);
                }
            }
        }
#pragma unroll
        for (int m = 0; m < 4; ++m)
#pragma unroll
            for (int r = 0; r < 4; ++r) {
                float d = dp[m][r];
                d += __shfl_xor(d, 1);
                d += __shfl_xor(d, 2);
                d += __shfl_xor(d, 4);
                d += __shfl_xor(d, 8);
                lrun[m][r] += d;
            }

        asm volatile("s_waitcnt lgkmcnt(0)" ::: "memory");
        __builtin_amdgcn_sched_barrier(0);

        // ---- O += P V ----
#pragma unroll
        for (int ks = 0; ks < 2; ++ks) {
            s16x8 pf[4], vf[4];
#pragma unroll
            for (int m = 0; m < 4; ++m)
                pf[m] = *(const s16x8*)(Ps + (q0 + m * 16 + lr) * 144 + ks * 64 + lg * 16);
#pragma unroll
            for (int n = 0; n < 4; ++n)
                vf[n] = *(const s16x8*)(Vt + (n * 16 + lr) * 144 + ks * 64 + lg * 16);
#pragma unroll
            for (int m = 0; m < 4; ++m)
#pragma unroll
                for (int n = 0; n < 4; ++n)
                    oacc[m][n] = __builtin_amdgcn_mfma_f32_16x16x32_bf16(pf[m], vf[n], oacc[m][n], 0, 0, 0);
        }
    }

    // ---- normalize + chunked LDS bounce + coalesced store ----
    float inv[4][4];
#pragma unroll
    for (int m = 0; m < 4; ++m)
#pragma unroll
        for (int r = 0; r < 4; ++r) inv[m][r] = 1.f / lrun[m][r];

    float* OL = (float*)lds;       // [128][68 f32] per chunk = 34816 B
#pragma unroll
    for (int c = 0; c < 2; ++c) {
        __syncthreads();
        if ((w >> 1) == c) {
            const int lq0 = q0 - c * 128;
#pragma unroll
            for (int m = 0; m < 4; ++m)
#pragma unroll
                for (int n = 0; n < 4; ++n)
#pragma unroll
                    for (int r = 0; r < 4; ++r) {
                        int lq = lq0 + m * 16 + lg * 4 + r;
                        int d = n * 16 + lr;
                        OL[lq * 68 + d] = oacc[m][n][r] * inv[m][r];
                    }
        }
        __syncthreads();
#pragma unroll
        for (int p = 0; p < 8; ++p) {
            int lq = p * 16 + (tid >> 4);
            int q = c * 128 + lq;
            int d4 = tid & 15;
            f32x4 v = *(const f32x4*)(OL + lq * 68 + d4 * 4);
            ushort4 hh;
            hh.x = bf16_rne(v[0]); hh.y = bf16_rne(v[1]);
            hh.z = bf16_rne(v[2]); hh.w = bf16_rne(v[3]);
            size_t o = (size_t)(b * 256 + q) * 512 + h * 64 + d4 * 4;
            *(ushort4*)(Oh + o) = hh;
        }
    }
}

// ---------------------------------------------------------------------------
// Prep: images -> patch-gathered RNE bf16 [8192][3072]
// ---------------------------------------------------------------------------
__global__ __launch_bounds__(256)
void img2planes_kernel(const float* __restrict__ img, uint16_t* __restrict__ Ph)
{
    int idx = blockIdx.x * 256 + threadIdx.x;   // over 8192*768
    if (idx >= 8192 * 768) return;
    int m = idx / 768, q = idx - (idx / 768) * 768;
    int k = q * 4;
    int bb = m >> 8, n = m & 255;
    int ph = k / 96, rem = k - ph * 96;
    int prow = ((n >> 4) << 5) + ph;
    int pcol0 = (n & 15) << 5;
    const float* s = img + (((size_t)bb * 512 + prow) * 512 + pcol0) * 3 + rem;
    float4 v = *(const float4*)s;
    ushort4 hh;
    hh.x = bf16_rne(v.x); hh.y = bf16_rne(v.y);
    hh.z = bf16_rne(v.z); hh.w = bf16_rne(v.w);
    *(ushort4*)(Ph + (size_t)m * 3072 + k) = hh;
}

__global__ __launch_bounds__(256)
void conv_direct_kernel(const float* __restrict__ src, uint16_t* __restrict__ dh, int total4)
{
    int idx = blockIdx.x * 256 + threadIdx.x;
    if (idx >= total4) return;
    float4 v = *(const float4*)(src + (size_t)idx * 4);
    ushort4 hh;
    hh.x = bf16_rne(v.x); hh.y = bf16_rne(v.y);
    hh.z = bf16_rne(v.z); hh.w = bf16_rne(v.w);
    *(ushort4*)(dh + (size_t)idx * 4) = hh;
}

__global__ __launch_bounds__(256)
void conv_transpose_kernel(const float* __restrict__ src, uint16_t* __restrict__ dh,
                           int K, int N)
{
    __shared__ float t[32][33];
    int k0 = blockIdx.x * 32, n0 = blockIdx.y * 32;
    const float* s = src + (size_t)blockIdx.z * K * N;
    size_t dbase = (size_t)blockIdx.z * N * K;
    int tid = threadIdx.x;
    {
        int kk = tid / 8, n4 = tid % 8;
        float4 v = *(const float4*)(s + (size_t)(k0 + kk) * N + n0 + n4 * 4);
        t[kk][n4 * 4 + 0] = v.x; t[kk][n4 * 4 + 1] = v.y;
        t[kk][n4 * 4 + 2] = v.z; t[kk][n4 * 4 + 3] = v.w;
    }
    __syncthreads();
    int nn = tid / 8, k4 = tid % 8;
    ushort4 hh;
    hh.x = bf16_rne(t[k4 * 4 + 0][nn]);
    hh.y = bf16_rne(t[k4 * 4 + 1][nn]);
    hh.z = bf16_rne(t[k4 * 4 + 2][nn]);
    hh.w = bf16_rne(t[k4 * 4 + 3][nn]);
    *(ushort4*)(dh + dbase + (size_t)(n0 + nn) * K + k0 + k4 * 4) = hh;
}

// ---------------------------------------------------------------------------
// LayerNorm over rows of 512; optionally emit RNE bf16.
// ---------------------------------------------------------------------------
template<bool PLANES>
__global__ __launch_bounds__(256)
void ln_kernel(const float* __restrict__ X, const float* __restrict__ g,
               const float* __restrict__ b, float* __restrict__ Y,
               uint16_t* __restrict__ Yh, int nrows)
{
    int wave = threadIdx.x >> 6;
    int lane = threadIdx.x & 63;
    int row = blockIdx.x * 4 + wave;
    if (row >= nrows) return;
    const float* x = X + (size_t)row * 512;
    float4 v0 = ((const float4*)x)[lane];
    float4 v1 = ((const float4*)x)[lane + 64];
    float s  = v0.x + v0.y + v0.z + v0.w + v1.x + v1.y + v1.z + v1.w;
    float sq = v0.x*v0.x + v0.y*v0.y + v0.z*v0.z + v0.w*v0.w
             + v1.x*v1.x + v1.y*v1.y + v1.z*v1.z + v1.w*v1.w;
#pragma unroll
    for (int off = 32; off > 0; off >>= 1) {
        s  += __shfl_down(s, off);
        sq += __shfl_down(sq, off);
    }
    s  = __shfl(s, 0);
    sq = __shfl(sq, 0);
    float mean = s * (1.f / 512.f);
    float var  = sq * (1.f / 512.f) - mean * mean;
    float rinv = rsqrtf(var + 1e-6f);
    float4 g0 = ((const float4*)g)[lane], g1 = ((const float4*)g)[lane + 64];
    float4 b0 = ((const float4*)b)[lane], b1 = ((const float4*)b)[lane + 64];
    float4 o0, o1;
    o0.x = (v0.x - mean) * rinv * g0.x + b0.x;
    o0.y = (v0.y - mean) * rinv * g0.y + b0.y;
    o0.z = (v0.z - mean) * rinv * g0.z + b0.z;
    o0.w = (v0.w - mean) * rinv * g0.w + b0.w;
    o1.x = (v1.x - mean) * rinv * g1.x + b1.x;
    o1.y = (v1.y - mean) * rinv * g1.y + b1.y;
    o1.z = (v1.z - mean) * rinv * g1.z + b1.z;
    o1.w = (v1.w - mean) * rinv * g1.w + b1.w;
    if (PLANES) {
        ushort4 hh0, hh1;
        hh0.x = bf16_rne(o0.x); hh0.y = bf16_rne(o0.y);
        hh0.z = bf16_rne(o0.z); hh0.w = bf16_rne(o0.w);
        hh1.x = bf16_rne(o1.x); hh1.y = bf16_rne(o1.y);
        hh1.z = bf16_rne(o1.z); hh1.w = bf16_rne(o1.w);
        size_t base = (size_t)row * 512;
        *(ushort4*)(Yh + base + lane * 4)       = hh0;
        *(ushort4*)(Yh + base + 256 + lane * 4) = hh1;
    } else {
        float* y = Y + (size_t)row * 512;
        ((float4*)y)[lane]      = o0;
        ((float4*)y)[lane + 64] = o1;
    }
}

// ---------------------------------------------------------------------------
// fp32 tiled GEMM (head layer 1 split-K)
// ---------------------------------------------------------------------------
template<int BM, int BN, int BK, int TM, int TN, bool SPLITK>
__global__ __launch_bounds__(256)
void gemm_kernel(const float* __restrict__ A, const float* __restrict__ B,
                 float* __restrict__ C, int M, int N, int K, int kchunk)
{
    constexpr int TX = BN / TN;
    constexpr int TY = BM / TM;
    static_assert(TX * TY == 256, "bad tile config");
    __shared__ float As[BK][BM + 4];
    __shared__ float Bs[BK][BN + 4];
    const int tid = threadIdx.x;
    const int tx  = tid % TX;
    const int ty  = tid / TX;
    const int bn0 = blockIdx.x * BN;
    const int bm0 = blockIdx.y * BM;
    int kstart = 0, kend = K;
    if (SPLITK) { kstart = blockIdx.z * kchunk; kend = kstart + kchunk; }
    float acc[TM][TN];
#pragma unroll
    for (int i = 0; i < TM; ++i)
#pragma unroll
        for (int j = 0; j < TN; ++j) acc[i][j] = 0.f;
    for (int k0 = kstart; k0 < kend; k0 += BK) {
        __syncthreads();
        constexpr int AV = BM * BK / 4 / 256;
#pragma unroll
        for (int r = 0; r < AV; ++r) {
            int idx = tid + r * 256;
            int k4 = idx % (BK / 4);
            int mm = idx / (BK / 4);
            float4 v = *(const float4*)(A + (size_t)(bm0 + mm) * K + k0 + k4 * 4);
            As[k4 * 4 + 0][mm] = v.x;
            As[k4 * 4 + 1][mm] = v.y;
            As[k4 * 4 + 2][mm] = v.z;
            As[k4 * 4 + 3][mm] = v.w;
        }
        constexpr int BV = BK * BN / 4 / 256;
#pragma unroll
        for (int r = 0; r < BV; ++r) {
            int idx = tid + r * 256;
            int n4 = idx % (BN / 4);
            int kk = idx / (BN / 4);
            float4 v = *(const float4*)(B + (size_t)(k0 + kk) * N + bn0 + n4 * 4);
            *(float4*)&Bs[kk][n4 * 4] = v;
        }
        __syncthreads();
#pragma unroll
        for (int kk = 0; kk < BK; ++kk) {
            float a[TM], b[TN];
#pragma unroll
            for (int i = 0; i < TM; i += 4)
                *(float4*)&a[i] = *(const float4*)&As[kk][ty * TM + i];
#pragma unroll
            for (int j = 0; j < TN; j += 4)
                *(float4*)&b[j] = *(const float4*)&Bs[kk][tx * TN + j];
#pragma unroll
            for (int i = 0; i < TM; ++i)
#pragma unroll
                for (int j = 0; j < TN; ++j)
                    acc[i][j] = fmaf(a[i], b[j], acc[i][j]);
        }
    }
    float* Cb = C;
    if (SPLITK) Cb += (size_t)blockIdx.z * M * N;
#pragma unroll
    for (int i = 0; i < TM; ++i) {
        int m = bm0 + ty * TM + i;
#pragma unroll
        for (int j = 0; j < TN; j += 4) {
            int n = bn0 + tx * TN + j;
            float4 v;
            v.x = acc[i][j + 0]; v.y = acc[i][j + 1];
            v.z = acc[i][j + 2]; v.w = acc[i][j + 3];
            *(float4*)(Cb + (size_t)m * N + n) = v;
        }
    }
}

__global__ __launch_bounds__(256)
void skinny_gemm_kernel(const float* __restrict__ A, const float* __restrict__ B,
                        float* __restrict__ P, int M, int N, int K, int kchunk)
{
    __shared__ float As[32][36];
    const int tid = threadIdx.x;
    const int tx  = tid & 63;
    const int ty  = tid >> 6;
    const int bn0 = blockIdx.x * 64;
    const int kstart = blockIdx.y * kchunk;
    const int kend   = kstart + kchunk;
    float acc[8];
#pragma unroll
    for (int i = 0; i < 8; ++i) acc[i] = 0.f;
    for (int k0 = kstart; k0 < kend; k0 += 32) {
        __syncthreads();
        {
            int row = tid >> 3;
            int k4  = tid & 7;
            float4 v = *(const float4*)(A + (size_t)row * K + k0 + k4 * 4);
            *(float4*)&As[row][k4 * 4] = v;
        }
        __syncthreads();
#pragma unroll 8
        for (int kk = 0; kk < 32; ++kk) {
            float b = B[(size_t)(k0 + kk) * N + bn0 + tx];
#pragma unroll
            for (int i = 0; i < 8; ++i)
                acc[i] = fmaf(As[ty * 8 + i][kk], b, acc[i]);
        }
    }
    float* Pb = P + (size_t)blockIdx.y * M * N;
#pragma unroll
    for (int i = 0; i < 8; ++i)
        Pb[(size_t)(ty * 8 + i) * N + bn0 + tx] = acc[i];
}

__global__ __launch_bounds__(256)
void reduce_gelu_kernel(const float* __restrict__ P, const float* __restrict__ bias,
                        float* __restrict__ Y, int total, int chunks, int N)
{
    int idx = blockIdx.x * 256 + threadIdx.x;
    if (idx >= total) return;
    float s = 0.f;
    for (int c = 0; c < chunks; ++c) s += P[(size_t)c * total + idx];
    s += bias[idx % N];
    Y[idx] = gelu_f(s);
}

template<bool GELU>
__global__ __launch_bounds__(256)
void small_gemm_kernel(const float* __restrict__ A, const float* __restrict__ B,
                       const float* __restrict__ bias, float* __restrict__ C,
                       int M, int N, int K)
{
    int idx = blockIdx.x * 256 + threadIdx.x;
    if (idx >= M * N) return;
    int m = idx / N, n = idx % N;
    const float* a = A + (size_t)m * K;
    float s = 0.f;
    for (int k = 0; k < K; ++k) s = fmaf(a[k], B[(size_t)k * N + n], s);
    s += bias[n];
    if (GELU) s = gelu_f(s);
    C[idx] = s;
}

// ---------------------------------------------------------------------------
extern "C" void kernel_launch(void* const* d_in, const int* in_sizes, int n_in,
                              void* d_out, int out_size, void* d_ws, size_t ws_size,
                              hipStream_t stream)
{
    const float* images     = (const float*)d_in[0];
    const float* W_proj     = (const float*)d_in[1];
    const float* b_proj     = (const float*)d_in[2];
    const float* pos_emb    = (const float*)d_in[3];
    const float* ln1_g      = (const float*)d_in[4];
    const float* ln1_b      = (const float*)d_in[5];
    const float* qkv_w      = (const float*)d_in[6];
    const float* qkv_b      = (const float*)d_in[7];
    const float* attn_out_w = (const float*)d_in[8];
    const float* attn_out_b = (const float*)d_in[9];
    const float* ln2_g      = (const float*)d_in[10];
    const float* ln2_b      = (const float*)d_in[11];
    const float* mlp_w1     = (const float*)d_in[12];
    const float* mlp_b1     = (const float*)d_in[13];
    const float* mlp_w2     = (const float*)d_in[14];
    const float* mlp_b2     = (const float*)d_in[15];
    const float* lnf_g      = (const float*)d_in[16];
    const float* lnf_b      = (const float*)d_in[17];
    const float* hW1 = (const float*)d_in[18];
    const float* hb1 = (const float*)d_in[19];
    const float* hW2 = (const float*)d_in[20];
    const float* hb2 = (const float*)d_in[21];
    const float* hW3 = (const float*)d_in[22];
    const float* hb3 = (const float*)d_in[23];
    const float* hW4 = (const float*)d_in[24];
    const float* hb4 = (const float*)d_in[25];
    const float* hW5 = (const float*)d_in[26];
    const float* hb5 = (const float*)d_in[27];
    const float* bbW = (const float*)d_in[28];
    const float* bbb = (const float*)d_in[29];

    // ---- workspace layout ----
    uint8_t* wsb = (uint8_t*)d_ws;
    size_t off = 0;
    auto alloc = [&](size_t bytes) { uint8_t* p = wsb + off; off += (bytes + 255) & ~(size_t)255; return p; };
    float*    X    = (float*)alloc(8192ull * 512 * 4);
    uint16_t* QKVb = (uint16_t*)alloc(8192ull * 1536 * 2);
    float*    T    = (float*)alloc(8192ull * 512 * 4);
    uint16_t* Xh   = (uint16_t*)alloc(8192ull * 512 * 2);
    uint16_t* Ohp  = (uint16_t*)alloc(8192ull * 512 * 2);
    uint16_t* Hh   = (uint16_t*)alloc(8192ull * 1024 * 2);
    uint16_t* Ph   = (uint16_t*)alloc(8192ull * 3072 * 2);
    uint16_t* WqH  = (uint16_t*)alloc(4ull * 1536 * 512 * 2);
    uint16_t* WaH  = (uint16_t*)alloc(4ull * 512 * 512 * 2);
    uint16_t* WpH  = (uint16_t*)alloc(512ull * 3072 * 2);
    uint16_t* W1H  = (uint16_t*)alloc(4ull * 1024 * 512 * 2);
    uint16_t* W2H  = (uint16_t*)alloc(4ull * 512 * 1024 * 2);
    float*    F1p  = (float*)alloc(128ull * 65536 * 4);
    float*    F1   = (float*)alloc(65536ull * 4);
    float*    P2   = (float*)alloc(64ull * 32768 * 4);
    float*    F2   = (float*)alloc(32768ull * 4);
    float*    P3   = (float*)alloc(32ull * 16384 * 4);
    float*    F3   = (float*)alloc(16384ull * 4);
    float*    P4   = (float*)alloc(16ull * 2048 * 4);
    float*    F4   = (float*)alloc(2048ull * 4);
    float*    F5   = (float*)alloc(1024ull * 4);

    dim3 blk(256);

    // ---- prep: convert weights + images to RNE bf16 ----
    img2planes_kernel<<<(8192 * 768 + 255) / 256, blk, 0, stream>>>(images, Ph);
    conv_direct_kernel<<<(4 * 1536 * 512 / 4 + 255) / 256, blk, 0, stream>>>(qkv_w, WqH, 4 * 1536 * 512 / 4);
    conv_direct_kernel<<<(4 * 512 * 512 / 4 + 255) / 256, blk, 0, stream>>>(attn_out_w, WaH, 4 * 512 * 512 / 4);
    conv_transpose_kernel<<<dim3(3072 / 32, 512 / 32, 1), blk, 0, stream>>>(W_proj, WpH, 3072, 512);
    conv_transpose_kernel<<<dim3(512 / 32, 1024 / 32, 4), blk, 0, stream>>>(mlp_w1, W1H, 512, 1024);
    conv_transpose_kernel<<<dim3(1024 / 32, 512 / 32, 4), blk, 0, stream>>>(mlp_w2, W2H, 1024, 512);

    // ---- patch embed: X = patches @ W_proj + b_proj + pos ----
    mfma_gemm<128, 128, true, false, false, true, true, false>
        <<<dim3(512 / 128, 8192 / 128), blk, 0, stream>>>(
            Ph, WpH, X, nullptr, b_proj, nullptr, pos_emb, 8192, 512, 3072);

    for (int l = 0; l < 4; ++l) {
        ln_kernel<true><<<2048, blk, 0, stream>>>(X, ln1_g + l * 512, ln1_b + l * 512,
                                                  nullptr, Xh, 8192);
        // qkv -> RNE bf16
        mfma_gemm<128, 128, true, false, false, false, false, true>
            <<<dim3(1536 / 128, 8192 / 128), blk, 0, stream>>>(
                Xh, WqH + (size_t)l * 1536 * 512, nullptr, QKVb,
                qkv_b + l * 1536, nullptr, nullptr, 8192, 1536, 512);
        mfma_attn<<<256, blk, 0, stream>>>(QKVb, Ohp);
        mfma_gemm<128, 128, true, false, true, false, true, false>
            <<<dim3(512 / 128, 8192 / 128), blk, 0, stream>>>(
                Ohp, WaH + (size_t)l * 512 * 512, X, nullptr,
                attn_out_b + l * 512, X, nullptr, 8192, 512, 512);
        ln_kernel<true><<<2048, blk, 0, stream>>>(X, ln2_g + l * 512, ln2_b + l * 512,
                                                  nullptr, Xh, 8192);
        mfma_gemm<128, 128, true, true, false, false, false, true>
            <<<dim3(1024 / 128, 8192 / 128), blk, 0, stream>>>(
                Xh, W1H + (size_t)l * 1024 * 512, nullptr, Hh,
                mlp_b1 + l * 1024, nullptr, nullptr, 8192, 1024, 512);
        mfma_gemm<128, 128, true, true, true, false, true, false>
            <<<dim3(512 / 128, 8192 / 128), blk, 0, stream>>>(
                Hh, W2H + (size_t)l * 512 * 1024, X, nullptr,
                mlp_b2 + l * 512, X, nullptr, 8192, 512, 1024);
    }

    // ---- final LN -> fp32 T ([32, 131072]) ----
    ln_kernel<false><<<2048, blk, 0, stream>>>(X, lnf_g, lnf_b, T, nullptr, 8192);

    // ---- MLP head ----
    gemm_kernel<32, 128, 32, 4, 4, true>
        <<<dim3(2048 / 128, 1, 128), blk, 0, stream>>>(
            T, hW1, F1p, 32, 2048, 131072, 131072 / 128);
    reduce_gelu_kernel<<<(65536 + 255) / 256, blk, 0, stream>>>(F1p, hb1, F1, 65536, 128, 2048);

    skinny_gemm_kernel<<<dim3(1024 / 64, 2048 / 32), blk, 0, stream>>>(F1, hW2, P2, 32, 1024, 2048, 32);
    reduce_gelu_kernel<<<(32768 + 255) / 256, blk, 0, stream>>>(P2, hb2, F2, 32768, 64, 1024);

    skinny_gemm_kernel<<<dim3(512 / 64, 1024 / 32), blk, 0, stream>>>(F2, hW3, P3, 32, 512, 1024, 32);
    reduce_gelu_kernel<<<(16384 + 255) / 256, blk, 0, stream>>>(P3, hb3, F3, 16384, 32, 512);

    skinny_gemm_kernel<<<dim3(64 / 64, 512 / 32), blk, 0, stream>>>(F3, hW4, P4, 32, 64, 512, 32);
    reduce_gelu_kernel<<<(2048 + 255) / 256, blk, 0, stream>>>(P4, hb4, F4, 2048, 16, 64);

    small_gemm_kernel<true><<<(32 * 32 + 255) / 256, blk, 0, stream>>>(F4, hW5, hb5, F5, 32, 32, 64);
    small_gemm_kernel<false><<<1, blk, 0, stream>>>(F5, bbW, bbb, (float*)d_out, 32, 4, 32);
}

// Round 10
// 1052.722 us; speedup vs baseline: 1.0688x; 1.0688x over previous
//
#include <hip/hip_runtime.h>
#include <cstdint>
#include <cstddef>

#define DEV __device__ __forceinline__

typedef float f32x4 __attribute__((ext_vector_type(4)));
typedef short s16x8 __attribute__((ext_vector_type(8)));

DEV float gelu_f(float x) { return 0.5f * x * (1.0f + erff(x * 0.70710678118654752f)); }

DEV uint32_t fbits(float x) { return __builtin_bit_cast(uint32_t, x); }

// round-to-nearest-even bf16
DEV uint16_t bf16_rne(float x) {
    uint32_t u = fbits(x);
    return (uint16_t)((u + 0x7FFFu + ((u >> 16) & 1u)) >> 16);
}

DEV void gload16(const void* g, void* l) {
    __builtin_amdgcn_global_load_lds(
        (const __attribute__((address_space(1))) uint32_t*)g,
        (__attribute__((address_space(3))) uint32_t*)l, 16, 0, 0);
}

// ---------------------------------------------------------------------------
// 1-pass bf16 MFMA GEMM.  A [M][K] bf16 (RNE), B [N][K] bf16 (RNE, k-major).
// C = A@B^T, fp32 accumulate.  2-phase double-buffered global_load_lds
// pipeline; XCD-aware block swizzle.  LDS capped at 2*HALF; epilogue bounces
// acc through LDS in 32-row chunks so global stores stay coalesced without
// inflating LDS (occupancy: 64x128 -> 24.6KB, 128x128 -> 32KB).
// NOTE: tiles for M=8192,N=512 ops stay 64x128 so grid >= 512 blocks
// (>=2 blocks/CU); 128^2 there gives 256 blocks = 1/CU and exposes the
// vmcnt(0) drain (R9 regression).
// ---------------------------------------------------------------------------
template<int BM, int BN, bool BIAS, bool GELU, bool RES, bool POS,
         bool OUTF32, bool OUTB16>
__global__ __launch_bounds__(256)
void mfma_gemm(const uint16_t* __restrict__ Ah, const uint16_t* __restrict__ Bh,
               float* __restrict__ C, uint16_t* __restrict__ Cb,
               const float* __restrict__ bias, const float* __restrict__ res,
               const float* __restrict__ pos, int M, int N, int K)
{
    constexpr int WTM = BM / 2, WTN = BN / 2;
    constexpr int FM = WTM / 16, FN = WTN / 16;
    constexpr int NA = BM / 16, NB = BN / 16;      // 1KB chunks per plane
    constexpr int TI = NA + NB;                    // gloads per K-step
    constexpr int TI4 = TI / 4;                    // per wave
    constexpr int HALF = (BM + BN) * 64;           // bytes per K-step
    constexpr int BNP = BN + 4;
    constexpr int CR  = 32;                        // epilogue chunk rows
    constexpr int NCH = BM / CR;
    static_assert(CR * BNP * 4 <= 2 * HALF, "chunk must fit LDS");

    __shared__ __align__(16) uint8_t smem[2 * HALF];
    constexpr int offB = BM * 64;

    const int tid = threadIdx.x;
    const int w = tid >> 6, l = tid & 63;
    const int wr = w >> 1, wc = w & 1;

    // XCD-aware bijective swizzle (all grids here are %8 == 0)
    const int gx = gridDim.x;
    const int nwg = gx * gridDim.y;
    const int lin = blockIdx.y * gx + blockIdx.x;
    const int cpx = nwg >> 3;
    const int swz = (lin & 7) * cpx + (lin >> 3);
    const int bxs = swz % gx, bys = swz / gx;
    const int bm0 = bys * BM, bn0 = bxs * BN;
    const size_t sK = (size_t)K * 2;

    const int srow  = l >> 2;
    const int sslot = (l & 3) ^ ((l >> 3) & 3);
    const uint8_t* gsrc[TI4];
    uint32_t loff[TI4];
#pragma unroll
    for (int j = 0; j < TI4; ++j) {
        int f = w * TI4 + j;
        int p = (f < NA) ? 0 : 1;
        int c = p ? (f - NA) : f;
        const uint16_t* base = p ? Bh : Ah;
        int rb = p ? bn0 : bm0;
        gsrc[j] = (const uint8_t*)base + (size_t)(rb + c * 16 + srow) * sK + sslot * 16;
        loff[j] = (uint32_t)((p ? offB : 0) + c * 1024);
    }

    const int lr = l & 15;
    const int sl16 = ((l >> 4) ^ ((lr >> 1) & 3)) * 16;
    const int aofs = (wr * WTM + lr) * 64 + sl16;
    const int bofs = (wc * WTN + lr) * 64 + sl16;

    f32x4 acc[FM][FN];
#pragma unroll
    for (int m = 0; m < FM; ++m)
#pragma unroll
        for (int n = 0; n < FN; ++n) acc[m][n] = (f32x4){0.f, 0.f, 0.f, 0.f};

    {
        const uint8_t* s0 = smem;
#pragma unroll
        for (int j = 0; j < TI4; ++j)
            gload16(gsrc[j], (void*)(s0 + loff[j]));
    }
    asm volatile("s_waitcnt vmcnt(0)" ::: "memory");
    __builtin_amdgcn_s_barrier();

    int cur = 0;
    for (int k0 = 0; k0 < K; k0 += 32) {
        const bool more = (k0 + 32 < K);
        if (more) {
            const size_t kb = (size_t)(k0 + 32) * 2;
            uint8_t* dst = smem + (cur ^ 1) * HALF;
#pragma unroll
            for (int j = 0; j < TI4; ++j)
                gload16(gsrc[j] + kb, dst + loff[j]);
        }
        const uint8_t* sb = smem + cur * HALF;
        s16x8 af[FM], bf[FN];
#pragma unroll
        for (int m = 0; m < FM; ++m)
            af[m] = *(const s16x8*)(sb + aofs + m * 1024);
#pragma unroll
        for (int n = 0; n < FN; ++n)
            bf[n] = *(const s16x8*)(sb + offB + bofs + n * 1024);
#pragma unroll
        for (int m = 0; m < FM; ++m)
#pragma unroll
            for (int n = 0; n < FN; ++n)
                acc[m][n] = __builtin_amdgcn_mfma_f32_16x16x32_bf16(af[m], bf[n], acc[m][n], 0, 0, 0);

        if (more) {
            asm volatile("s_waitcnt vmcnt(0)" ::: "memory");
            __builtin_amdgcn_s_barrier();
        }
        cur ^= 1;
    }

    // ---- epilogue: chunked LDS bounce (CR rows/pass, LDS stays 2*HALF) ----
    float* lf = (float*)smem;
    const int r4 = (l >> 4) * 4;

    constexpr int C4PR = BN / 4;
    constexpr int RPP  = 256 / C4PR;
    const int rr = tid / C4PR, c4 = tid % C4PR;
    const int nn = bn0 + c4 * 4;

    float4 bv = {0.f, 0.f, 0.f, 0.f};
    if (BIAS) bv = *(const float4*)(bias + nn);

#pragma unroll
    for (int c = 0; c < NCH; ++c) {
        __syncthreads();   // prev chunk stores / K-loop reads done
        if (wr == (c * CR) / WTM) {
            const int mlo = ((c * CR) % WTM) / 16;
#pragma unroll
            for (int mi = 0; mi < CR / 16; ++mi) {
                int m = mlo + mi;
#pragma unroll
                for (int n = 0; n < FN; ++n) {
                    int col = wc * WTN + n * 16 + lr;
#pragma unroll
                    for (int r = 0; r < 4; ++r) {
                        int lrow = mi * 16 + r4 + r;
                        lf[lrow * BNP + col] = acc[m][n][r];
                    }
                }
            }
        }
        __syncthreads();
#pragma unroll
        for (int p = 0; p < CR / RPP; ++p) {
            int row = p * RPP + rr;
            int mm = bm0 + c * CR + row;
            float4 v = *(const float4*)&lf[row * BNP + c4 * 4];
            float* vp = &v.x;
            const float* bp = &bv.x;
#pragma unroll
            for (int q = 0; q < 4; ++q) {
                float x = vp[q];
                if (BIAS) x += bp[q];
                if (GELU) x = gelu_f(x);
                vp[q] = x;
            }
            if (RES) {
                float4 rv = *(const float4*)(res + (size_t)mm * N + nn);
                v.x += rv.x; v.y += rv.y; v.z += rv.z; v.w += rv.w;
            }
            if (POS) {
                float4 pv = *(const float4*)(pos + (size_t)(mm & 255) * N + nn);
                v.x += pv.x; v.y += pv.y; v.z += pv.z; v.w += pv.w;
            }
            size_t o = (size_t)mm * N + nn;
            if (OUTF32) *(float4*)(C + o) = v;
            if (OUTB16) {
                ushort4 hh;
                hh.x = bf16_rne(v.x); hh.y = bf16_rne(v.y);
                hh.z = bf16_rne(v.z); hh.w = bf16_rne(v.w);
                *(ushort4*)(Cb + o) = hh;
            }
        }
    }
}

// ---------------------------------------------------------------------------
// MFMA flash-style attention over RNE-bf16 QKV [8192][1536] u16.
// One block per (b,h); 4 waves x 64 queries.  Q held in REGISTERS.
// K/V staged in padded LDS.  LDS = 54 KB.  Softmax fp32, no max-subtraction.
// ---------------------------------------------------------------------------
__global__ __launch_bounds__(256)
void mfma_attn(const uint16_t* __restrict__ QKVb, uint16_t* __restrict__ Oh)
{
    __shared__ __align__(16) uint8_t lds[55296];
    uint8_t* Ks = lds;              // [64][144B]
    uint8_t* Vt = lds + 9216;       // [64][144B]   (rows = d, cols = k)
    uint8_t* Ps = lds + 18432;      // [256][144B]

    const int tid = threadIdx.x;
    const int w = tid >> 6, l = tid & 63;
    const int lr = l & 15, lg = l >> 4;
    const int bh = blockIdx.x;
    const int b = bh >> 3, h = bh & 7;
    const uint16_t* base = QKVb + (size_t)b * 256 * 1536 + h * 64;
    const int q0 = w * 64;

    // ---- Q fragments direct to registers (lane-private, reused all kt) ----
    s16x8 qreg[2][4];
#pragma unroll
    for (int ks = 0; ks < 2; ++ks)
#pragma unroll
        for (int m = 0; m < 4; ++m)
            qreg[ks][m] = *(const s16x8*)(base + (size_t)(q0 + m * 16 + lr) * 1536 + ks * 32 + lg * 8);

    f32x4 oacc[4][4];
    float lrun[4][4];
#pragma unroll
    for (int m = 0; m < 4; ++m)
#pragma unroll
        for (int n = 0; n < 4; ++n) { oacc[m][n] = (f32x4){0.f,0.f,0.f,0.f}; lrun[m][n] = 0.f; }

    for (int kt = 0; kt < 4; ++kt) {
        __syncthreads();   // prev tile reads done
        {
            int r = tid >> 2, sp = (tid & 3) * 2;
            const uint16_t* kp = base + (size_t)(kt * 64 + r) * 1536 + 512;
#pragma unroll
            for (int ss = 0; ss < 2; ++ss) {
                int s = sp + ss;
                *(s16x8*)(Ks + r * 144 + s * 16) = *(const s16x8*)(kp + s * 8);
            }
        }
        {
            int k = tid & 63, d0 = (tid >> 6) * 16;
            const uint16_t* vp = base + (size_t)(kt * 64 + k) * 1536 + 1024 + d0;
            s16x8 a = *(const s16x8*)(vp);
            s16x8 c = *(const s16x8*)(vp + 8);
#pragma unroll
            for (int i = 0; i < 8; ++i) {
                *(uint16_t*)(Vt + (d0 + i) * 144 + k * 2)     = (uint16_t)a[i];
                *(uint16_t*)(Vt + (d0 + 8 + i) * 144 + k * 2) = (uint16_t)c[i];
            }
        }
        __syncthreads();   // staging visible

        // ---- S = Q K^T ----
        f32x4 sacc[4][4];
#pragma unroll
        for (int m = 0; m < 4; ++m)
#pragma unroll
            for (int n = 0; n < 4; ++n) sacc[m][n] = (f32x4){0.f,0.f,0.f,0.f};
#pragma unroll
        for (int ks = 0; ks < 2; ++ks) {
            s16x8 kf[4];
#pragma unroll
            for (int n = 0; n < 4; ++n)
                kf[n] = *(const s16x8*)(Ks + (n * 16 + lr) * 144 + ks * 64 + lg * 16);
#pragma unroll
            for (int m = 0; m < 4; ++m)
#pragma unroll
                for (int n = 0; n < 4; ++n)
                    sacc[m][n] = __builtin_amdgcn_mfma_f32_16x16x32_bf16(qreg[ks][m], kf[n], sacc[m][n], 0, 0, 0);
        }

        // ---- exp + P write + denominator ----
        float dp[4][4];
#pragma unroll
        for (int m = 0; m < 4; ++m)
#pragma unroll
            for (int r = 0; r < 4; ++r) dp[m][r] = 0.f;
#pragma unroll
        for (int m = 0; m < 4; ++m) {
#pragma unroll
            for (int n = 0; n < 4; ++n) {
#pragma unroll
                for (int r = 0; r < 4; ++r) {
                    float e = __expf(sacc[m][n][r] * 0.125f);
                    dp[m][r] += e;
                    int q = q0 + m * 16 + lg * 4 + r;
                    int k = n * 16 + lr;
                    *(uint16_t*)(Ps + q * 144 + k * 2) = bf16_rne(e);
                }
            }
        }
#pragma unroll
        for (int m = 0; m < 4; ++m)
#pragma unroll
            for (int r = 0; r < 4; ++r) {
                float d = dp[m][r];
                d += __shfl_xor(d, 1);
                d += __shfl_xor(d, 2);
                d += __shfl_xor(d, 4);
                d += __shfl_xor(d, 8);
                lrun[m][r] += d;
            }

        asm volatile("s_waitcnt lgkmcnt(0)" ::: "memory");
        __builtin_amdgcn_sched_barrier(0);

        // ---- O += P V ----
#pragma unroll
        for (int ks = 0; ks < 2; ++ks) {
            s16x8 pf[4], vf[4];
#pragma unroll
            for (int m = 0; m < 4; ++m)
                pf[m] = *(const s16x8*)(Ps + (q0 + m * 16 + lr) * 144 + ks * 64 + lg * 16);
#pragma unroll
            for (int n = 0; n < 4; ++n)
                vf[n] = *(const s16x8*)(Vt + (n * 16 + lr) * 144 + ks * 64 + lg * 16);
#pragma unroll
            for (int m = 0; m < 4; ++m)
#pragma unroll
                for (int n = 0; n < 4; ++n)
                    oacc[m][n] = __builtin_amdgcn_mfma_f32_16x16x32_bf16(pf[m], vf[n], oacc[m][n], 0, 0, 0);
        }
    }

    // ---- normalize + chunked LDS bounce + coalesced store ----
    float inv[4][4];
#pragma unroll
    for (int m = 0; m < 4; ++m)
#pragma unroll
        for (int r = 0; r < 4; ++r) inv[m][r] = 1.f / lrun[m][r];

    float* OL = (float*)lds;       // [128][68 f32] per chunk = 34816 B
#pragma unroll
    for (int c = 0; c < 2; ++c) {
        __syncthreads();
        if ((w >> 1) == c) {
            const int lq0 = q0 - c * 128;
#pragma unroll
            for (int m = 0; m < 4; ++m)
#pragma unroll
                for (int n = 0; n < 4; ++n)
#pragma unroll
                    for (int r = 0; r < 4; ++r) {
                        int lq = lq0 + m * 16 + lg * 4 + r;
                        int d = n * 16 + lr;
                        OL[lq * 68 + d] = oacc[m][n][r] * inv[m][r];
                    }
        }
        __syncthreads();
#pragma unroll
        for (int p = 0; p < 8; ++p) {
            int lq = p * 16 + (tid >> 4);
            int q = c * 128 + lq;
            int d4 = tid & 15;
            f32x4 v = *(const f32x4*)(OL + lq * 68 + d4 * 4);
            ushort4 hh;
            hh.x = bf16_rne(v[0]); hh.y = bf16_rne(v[1]);
            hh.z = bf16_rne(v[2]); hh.w = bf16_rne(v[3]);
            size_t o = (size_t)(b * 256 + q) * 512 + h * 64 + d4 * 4;
            *(ushort4*)(Oh + o) = hh;
        }
    }
}

// ---------------------------------------------------------------------------
// Prep: images -> patch-gathered RNE bf16 [8192][3072]
// ---------------------------------------------------------------------------
__global__ __launch_bounds__(256)
void img2planes_kernel(const float* __restrict__ img, uint16_t* __restrict__ Ph)
{
    int idx = blockIdx.x * 256 + threadIdx.x;   // over 8192*768
    if (idx >= 8192 * 768) return;
    int m = idx / 768, q = idx - (idx / 768) * 768;
    int k = q * 4;
    int bb = m >> 8, n = m & 255;
    int ph = k / 96, rem = k - ph * 96;
    int prow = ((n >> 4) << 5) + ph;
    int pcol0 = (n & 15) << 5;
    const float* s = img + (((size_t)bb * 512 + prow) * 512 + pcol0) * 3 + rem;
    float4 v = *(const float4*)s;
    ushort4 hh;
    hh.x = bf16_rne(v.x); hh.y = bf16_rne(v.y);
    hh.z = bf16_rne(v.z); hh.w = bf16_rne(v.w);
    *(ushort4*)(Ph + (size_t)m * 3072 + k) = hh;
}

__global__ __launch_bounds__(256)
void conv_direct_kernel(const float* __restrict__ src, uint16_t* __restrict__ dh, int total4)
{
    int idx = blockIdx.x * 256 + threadIdx.x;
    if (idx >= total4) return;
    float4 v = *(const float4*)(src + (size_t)idx * 4);
    ushort4 hh;
    hh.x = bf16_rne(v.x); hh.y = bf16_rne(v.y);
    hh.z = bf16_rne(v.z); hh.w = bf16_rne(v.w);
    *(ushort4*)(dh + (size_t)idx * 4) = hh;
}

__global__ __launch_bounds__(256)
void conv_transpose_kernel(const float* __restrict__ src, uint16_t* __restrict__ dh,
                           int K, int N)
{
    __shared__ float t[32][33];
    int k0 = blockIdx.x * 32, n0 = blockIdx.y * 32;
    const float* s = src + (size_t)blockIdx.z * K * N;
    size_t dbase = (size_t)blockIdx.z * N * K;
    int tid = threadIdx.x;
    {
        int kk = tid / 8, n4 = tid % 8;
        float4 v = *(const float4*)(s + (size_t)(k0 + kk) * N + n0 + n4 * 4);
        t[kk][n4 * 4 + 0] = v.x; t[kk][n4 * 4 + 1] = v.y;
        t[kk][n4 * 4 + 2] = v.z; t[kk][n4 * 4 + 3] = v.w;
    }
    __syncthreads();
    int nn = tid / 8, k4 = tid % 8;
    ushort4 hh;
    hh.x = bf16_rne(t[k4 * 4 + 0][nn]);
    hh.y = bf16_rne(t[k4 * 4 + 1][nn]);
    hh.z = bf16_rne(t[k4 * 4 + 2][nn]);
    hh.w = bf16_rne(t[k4 * 4 + 3][nn]);
    *(ushort4*)(dh + dbase + (size_t)(n0 + nn) * K + k0 + k4 * 4) = hh;
}

// ---------------------------------------------------------------------------
// LayerNorm over rows of 512; optionally emit RNE bf16.
// ---------------------------------------------------------------------------
template<bool PLANES>
__global__ __launch_bounds__(256)
void ln_kernel(const float* __restrict__ X, const float* __restrict__ g,
               const float* __restrict__ b, float* __restrict__ Y,
               uint16_t* __restrict__ Yh, int nrows)
{
    int wave = threadIdx.x >> 6;
    int lane = threadIdx.x & 63;
    int row = blockIdx.x * 4 + wave;
    if (row >= nrows) return;
    const float* x = X + (size_t)row * 512;
    float4 v0 = ((const float4*)x)[lane];
    float4 v1 = ((const float4*)x)[lane + 64];
    float s  = v0.x + v0.y + v0.z + v0.w + v1.x + v1.y + v1.z + v1.w;
    float sq = v0.x*v0.x + v0.y*v0.y + v0.z*v0.z + v0.w*v0.w
             + v1.x*v1.x + v1.y*v1.y + v1.z*v1.z + v1.w*v1.w;
#pragma unroll
    for (int off = 32; off > 0; off >>= 1) {
        s  += __shfl_down(s, off);
        sq += __shfl_down(sq, off);
    }
    s  = __shfl(s, 0);
    sq = __shfl(sq, 0);
    float mean = s * (1.f / 512.f);
    float var  = sq * (1.f / 512.f) - mean * mean;
    float rinv = rsqrtf(var + 1e-6f);
    float4 g0 = ((const float4*)g)[lane], g1 = ((const float4*)g)[lane + 64];
    float4 b0 = ((const float4*)b)[lane], b1 = ((const float4*)b)[lane + 64];
    float4 o0, o1;
    o0.x = (v0.x - mean) * rinv * g0.x + b0.x;
    o0.y = (v0.y - mean) * rinv * g0.y + b0.y;
    o0.z = (v0.z - mean) * rinv * g0.z + b0.z;
    o0.w = (v0.w - mean) * rinv * g0.w + b0.w;
    o1.x = (v1.x - mean) * rinv * g1.x + b1.x;
    o1.y = (v1.y - mean) * rinv * g1.y + b1.y;
    o1.z = (v1.z - mean) * rinv * g1.z + b1.z;
    o1.w = (v1.w - mean) * rinv * g1.w + b1.w;
    if (PLANES) {
        ushort4 hh0, hh1;
        hh0.x = bf16_rne(o0.x); hh0.y = bf16_rne(o0.y);
        hh0.z = bf16_rne(o0.z); hh0.w = bf16_rne(o0.w);
        hh1.x = bf16_rne(o1.x); hh1.y = bf16_rne(o1.y);
        hh1.z = bf16_rne(o1.z); hh1.w = bf16_rne(o1.w);
        size_t base = (size_t)row * 512;
        *(ushort4*)(Yh + base + lane * 4)       = hh0;
        *(ushort4*)(Yh + base + 256 + lane * 4) = hh1;
    } else {
        float* y = Y + (size_t)row * 512;
        ((float4*)y)[lane]      = o0;
        ((float4*)y)[lane + 64] = o1;
    }
}

// ---------------------------------------------------------------------------
// fp32 tiled GEMM (head layer 1 split-K)
// ---------------------------------------------------------------------------
template<int BM, int BN, int BK, int TM, int TN, bool SPLITK>
__global__ __launch_bounds__(256)
void gemm_kernel(const float* __restrict__ A, const float* __restrict__ B,
                 float* __restrict__ C, int M, int N, int K, int kchunk)
{
    constexpr int TX = BN / TN;
    constexpr int TY = BM / TM;
    static_assert(TX * TY == 256, "bad tile config");
    __shared__ float As[BK][BM + 4];
    __shared__ float Bs[BK][BN + 4];
    const int tid = threadIdx.x;
    const int tx  = tid % TX;
    const int ty  = tid / TX;
    const int bn0 = blockIdx.x * BN;
    const int bm0 = blockIdx.y * BM;
    int kstart = 0, kend = K;
    if (SPLITK) { kstart = blockIdx.z * kchunk; kend = kstart + kchunk; }
    float acc[TM][TN];
#pragma unroll
    for (int i = 0; i < TM; ++i)
#pragma unroll
        for (int j = 0; j < TN; ++j) acc[i][j] = 0.f;
    for (int k0 = kstart; k0 < kend; k0 += BK) {
        __syncthreads();
        constexpr int AV = BM * BK / 4 / 256;
#pragma unroll
        for (int r = 0; r < AV; ++r) {
            int idx = tid + r * 256;
            int k4 = idx % (BK / 4);
            int mm = idx / (BK / 4);
            float4 v = *(const float4*)(A + (size_t)(bm0 + mm) * K + k0 + k4 * 4);
            As[k4 * 4 + 0][mm] = v.x;
            As[k4 * 4 + 1][mm] = v.y;
            As[k4 * 4 + 2][mm] = v.z;
            As[k4 * 4 + 3][mm] = v.w;
        }
        constexpr int BV = BK * BN / 4 / 256;
#pragma unroll
        for (int r = 0; r < BV; ++r) {
            int idx = tid + r * 256;
            int n4 = idx % (BN / 4);
            int kk = idx / (BN / 4);
            float4 v = *(const float4*)(B + (size_t)(k0 + kk) * N + bn0 + n4 * 4);
            *(float4*)&Bs[kk][n4 * 4] = v;
        }
        __syncthreads();
#pragma unroll
        for (int kk = 0; kk < BK; ++kk) {
            float a[TM], b[TN];
#pragma unroll
            for (int i = 0; i < TM; i += 4)
                *(float4*)&a[i] = *(const float4*)&As[kk][ty * TM + i];
#pragma unroll
            for (int j = 0; j < TN; j += 4)
                *(float4*)&b[j] = *(const float4*)&Bs[kk][tx * TN + j];
#pragma unroll
            for (int i = 0; i < TM; ++i)
#pragma unroll
                for (int j = 0; j < TN; ++j)
                    acc[i][j] = fmaf(a[i], b[j], acc[i][j]);
        }
    }
    float* Cb = C;
    if (SPLITK) Cb += (size_t)blockIdx.z * M * N;
#pragma unroll
    for (int i = 0; i < TM; ++i) {
        int m = bm0 + ty * TM + i;
#pragma unroll
        for (int j = 0; j < TN; j += 4) {
            int n = bn0 + tx * TN + j;
            float4 v;
            v.x = acc[i][j + 0]; v.y = acc[i][j + 1];
            v.z = acc[i][j + 2]; v.w = acc[i][j + 3];
            *(float4*)(Cb + (size_t)m * N + n) = v;
        }
    }
}

__global__ __launch_bounds__(256)
void skinny_gemm_kernel(const float* __restrict__ A, const float* __restrict__ B,
                        float* __restrict__ P, int M, int N, int K, int kchunk)
{
    __shared__ float As[32][36];
    const int tid = threadIdx.x;
    const int tx  = tid & 63;
    const int ty  = tid >> 6;
    const int bn0 = blockIdx.x * 64;
    const int kstart = blockIdx.y * kchunk;
    const int kend   = kstart + kchunk;
    float acc[8];
#pragma unroll
    for (int i = 0; i < 8; ++i) acc[i] = 0.f;
    for (int k0 = kstart; k0 < kend; k0 += 32) {
        __syncthreads();
        {
            int row = tid >> 3;
            int k4  = tid & 7;
            float4 v = *(const float4*)(A + (size_t)row * K + k0 + k4 * 4);
            *(float4*)&As[row][k4 * 4] = v;
        }
        __syncthreads();
#pragma unroll 8
        for (int kk = 0; kk < 32; ++kk) {
            float b = B[(size_t)(k0 + kk) * N + bn0 + tx];
#pragma unroll
            for (int i = 0; i < 8; ++i)
                acc[i] = fmaf(As[ty * 8 + i][kk], b, acc[i]);
        }
    }
    float* Pb = P + (size_t)blockIdx.y * M * N;
#pragma unroll
    for (int i = 0; i < 8; ++i)
        Pb[(size_t)(ty * 8 + i) * N + bn0 + tx] = acc[i];
}

__global__ __launch_bounds__(256)
void reduce_gelu_kernel(const float* __restrict__ P, const float* __restrict__ bias,
                        float* __restrict__ Y, int total, int chunks, int N)
{
    int idx = blockIdx.x * 256 + threadIdx.x;
    if (idx >= total) return;
    float s = 0.f;
    for (int c = 0; c < chunks; ++c) s += P[(size_t)c * total + idx];
    s += bias[idx % N];
    Y[idx] = gelu_f(s);
}

template<bool GELU>
__global__ __launch_bounds__(256)
void small_gemm_kernel(const float* __restrict__ A, const float* __restrict__ B,
                       const float* __restrict__ bias, float* __restrict__ C,
                       int M, int N, int K)
{
    int idx = blockIdx.x * 256 + threadIdx.x;
    if (idx >= M * N) return;
    int m = idx / N, n = idx % N;
    const float* a = A + (size_t)m * K;
    float s = 0.f;
    for (int k = 0; k < K; ++k) s = fmaf(a[k], B[(size_t)k * N + n], s);
    s += bias[n];
    if (GELU) s = gelu_f(s);
    C[idx] = s;
}

// ---------------------------------------------------------------------------
extern "C" void kernel_launch(void* const* d_in, const int* in_sizes, int n_in,
                              void* d_out, int out_size, void* d_ws, size_t ws_size,
                              hipStream_t stream)
{
    const float* images     = (const float*)d_in[0];
    const float* W_proj     = (const float*)d_in[1];
    const float* b_proj     = (const float*)d_in[2];
    const float* pos_emb    = (const float*)d_in[3];
    const float* ln1_g      = (const float*)d_in[4];
    const float* ln1_b      = (const float*)d_in[5];
    const float* qkv_w      = (const float*)d_in[6];
    const float* qkv_b      = (const float*)d_in[7];
    const float* attn_out_w = (const float*)d_in[8];
    const float* attn_out_b = (const float*)d_in[9];
    const float* ln2_g      = (const float*)d_in[10];
    const float* ln2_b      = (const float*)d_in[11];
    const float* mlp_w1     = (const float*)d_in[12];
    const float* mlp_b1     = (const float*)d_in[13];
    const float* mlp_w2     = (const float*)d_in[14];
    const float* mlp_b2     = (const float*)d_in[15];
    const float* lnf_g      = (const float*)d_in[16];
    const float* lnf_b      = (const float*)d_in[17];
    const float* hW1 = (const float*)d_in[18];
    const float* hb1 = (const float*)d_in[19];
    const float* hW2 = (const float*)d_in[20];
    const float* hb2 = (const float*)d_in[21];
    const float* hW3 = (const float*)d_in[22];
    const float* hb3 = (const float*)d_in[23];
    const float* hW4 = (const float*)d_in[24];
    const float* hb4 = (const float*)d_in[25];
    const float* hW5 = (const float*)d_in[26];
    const float* hb5 = (const float*)d_in[27];
    const float* bbW = (const float*)d_in[28];
    const float* bbb = (const float*)d_in[29];

    // ---- workspace layout ----
    uint8_t* wsb = (uint8_t*)d_ws;
    size_t off = 0;
    auto alloc = [&](size_t bytes) { uint8_t* p = wsb + off; off += (bytes + 255) & ~(size_t)255; return p; };
    float*    X    = (float*)alloc(8192ull * 512 * 4);
    uint16_t* QKVb = (uint16_t*)alloc(8192ull * 1536 * 2);
    float*    T    = (float*)alloc(8192ull * 512 * 4);
    uint16_t* Xh   = (uint16_t*)alloc(8192ull * 512 * 2);
    uint16_t* Ohp  = (uint16_t*)alloc(8192ull * 512 * 2);
    uint16_t* Hh   = (uint16_t*)alloc(8192ull * 1024 * 2);
    uint16_t* Ph   = (uint16_t*)alloc(8192ull * 3072 * 2);
    uint16_t* WqH  = (uint16_t*)alloc(4ull * 1536 * 512 * 2);
    uint16_t* WaH  = (uint16_t*)alloc(4ull * 512 * 512 * 2);
    uint16_t* WpH  = (uint16_t*)alloc(512ull * 3072 * 2);
    uint16_t* W1H  = (uint16_t*)alloc(4ull * 1024 * 512 * 2);
    uint16_t* W2H  = (uint16_t*)alloc(4ull * 512 * 1024 * 2);
    float*    F1p  = (float*)alloc(128ull * 65536 * 4);
    float*    F1   = (float*)alloc(65536ull * 4);
    float*    P2   = (float*)alloc(64ull * 32768 * 4);
    float*    F2   = (float*)alloc(32768ull * 4);
    float*    P3   = (float*)alloc(32ull * 16384 * 4);
    float*    F3   = (float*)alloc(16384ull * 4);
    float*    P4   = (float*)alloc(16ull * 2048 * 4);
    float*    F4   = (float*)alloc(2048ull * 4);
    float*    F5   = (float*)alloc(1024ull * 4);

    dim3 blk(256);

    // ---- prep: convert weights + images to RNE bf16 ----
    img2planes_kernel<<<(8192 * 768 + 255) / 256, blk, 0, stream>>>(images, Ph);
    conv_direct_kernel<<<(4 * 1536 * 512 / 4 + 255) / 256, blk, 0, stream>>>(qkv_w, WqH, 4 * 1536 * 512 / 4);
    conv_direct_kernel<<<(4 * 512 * 512 / 4 + 255) / 256, blk, 0, stream>>>(attn_out_w, WaH, 4 * 512 * 512 / 4);
    conv_transpose_kernel<<<dim3(3072 / 32, 512 / 32, 1), blk, 0, stream>>>(W_proj, WpH, 3072, 512);
    conv_transpose_kernel<<<dim3(512 / 32, 1024 / 32, 4), blk, 0, stream>>>(mlp_w1, W1H, 512, 1024);
    conv_transpose_kernel<<<dim3(1024 / 32, 512 / 32, 4), blk, 0, stream>>>(mlp_w2, W2H, 1024, 512);

    // ---- patch embed: X = patches @ W_proj + b_proj + pos   (64x128 tile) ----
    mfma_gemm<64, 128, true, false, false, true, true, false>
        <<<dim3(512 / 128, 8192 / 64), blk, 0, stream>>>(
            Ph, WpH, X, nullptr, b_proj, nullptr, pos_emb, 8192, 512, 3072);

    for (int l = 0; l < 4; ++l) {
        ln_kernel<true><<<2048, blk, 0, stream>>>(X, ln1_g + l * 512, ln1_b + l * 512,
                                                  nullptr, Xh, 8192);
        // qkv -> RNE bf16 (128^2 tile, grid 768)
        mfma_gemm<128, 128, true, false, false, false, false, true>
            <<<dim3(1536 / 128, 8192 / 128), blk, 0, stream>>>(
                Xh, WqH + (size_t)l * 1536 * 512, nullptr, QKVb,
                qkv_b + l * 1536, nullptr, nullptr, 8192, 1536, 512);
        mfma_attn<<<256, blk, 0, stream>>>(QKVb, Ohp);
        // attn_out (64x128 tile, grid 512)
        mfma_gemm<64, 128, true, false, true, false, true, false>
            <<<dim3(512 / 128, 8192 / 64), blk, 0, stream>>>(
                Ohp, WaH + (size_t)l * 512 * 512, X, nullptr,
                attn_out_b + l * 512, X, nullptr, 8192, 512, 512);
        ln_kernel<true><<<2048, blk, 0, stream>>>(X, ln2_g + l * 512, ln2_b + l * 512,
                                                  nullptr, Xh, 8192);
        // mlp1 (128^2 tile, grid 512)
        mfma_gemm<128, 128, true, true, false, false, false, true>
            <<<dim3(1024 / 128, 8192 / 128), blk, 0, stream>>>(
                Xh, W1H + (size_t)l * 1024 * 512, nullptr, Hh,
                mlp_b1 + l * 1024, nullptr, nullptr, 8192, 1024, 512);
        // mlp2 (64x128 tile, grid 512)
        mfma_gemm<64, 128, true, true, true, false, true, false>
            <<<dim3(512 / 128, 8192 / 64), blk, 0, stream>>>(
                Hh, W2H + (size_t)l * 512 * 1024, X, nullptr,
                mlp_b2 + l * 512, X, nullptr, 8192, 512, 1024);
    }

    // ---- final LN -> fp32 T ([32, 131072]) ----
    ln_kernel<false><<<2048, blk, 0, stream>>>(X, lnf_g, lnf_b, T, nullptr, 8192);

    // ---- MLP head ----
    gemm_kernel<32, 128, 32, 4, 4, true>
        <<<dim3(2048 / 128, 1, 128), blk, 0, stream>>>(
            T, hW1, F1p, 32, 2048, 131072, 131072 / 128);
    reduce_gelu_kernel<<<(65536 + 255) / 256, blk, 0, stream>>>(F1p, hb1, F1, 65536, 128, 2048);

    skinny_gemm_kernel<<<dim3(1024 / 64, 2048 / 32), blk, 0, stream>>>(F1, hW2, P2, 32, 1024, 2048, 32);
    reduce_gelu_kernel<<<(32768 + 255) / 256, blk, 0, stream>>>(P2, hb2, F2, 32768, 64, 1024);

    skinny_gemm_kernel<<<dim3(512 / 64, 1024 / 32), blk, 0, stream>>>(F2, hW3, P3, 32, 512, 1024, 32);
    reduce_gelu_kernel<<<(16384 + 255) / 256, blk, 0, stream>>>(P3, hb3, F3, 16384, 32, 512);

    skinny_gemm_kernel<<<dim3(64 / 64, 512 / 32), blk, 0, stream>>>(F3, hW4, P4, 32, 64, 512, 32);
    reduce_gelu_kernel<<<(2048 + 255) / 256, blk, 0, stream>>>(P4, hb4, F4, 2048, 16, 64);

    small_gemm_kernel<true><<<(32 * 32 + 255) / 256, blk, 0, stream>>>(F4, hW5, hb5, F5, 32, 32, 64);
    small_gemm_kernel<false><<<1, blk, 0, stream>>>(F5, bbW, bbb, (float*)d_out, 32, 4, 32);
}

// Round 11
// 995.517 us; speedup vs baseline: 1.1302x; 1.0575x over previous
//
#include <hip/hip_runtime.h>
#include <cstdint>
#include <cstddef>

#define DEV __device__ __forceinline__

typedef float f32x4 __attribute__((ext_vector_type(4)));
typedef short s16x8 __attribute__((ext_vector_type(8)));

DEV float gelu_f(float x) { return 0.5f * x * (1.0f + erff(x * 0.70710678118654752f)); }

DEV uint32_t fbits(float x) { return __builtin_bit_cast(uint32_t, x); }

// round-to-nearest-even bf16
DEV uint16_t bf16_rne(float x) {
    uint32_t u = fbits(x);
    return (uint16_t)((u + 0x7FFFu + ((u >> 16) & 1u)) >> 16);
}

DEV void gload16(const void* g, void* l) {
    __builtin_amdgcn_global_load_lds(
        (const __attribute__((address_space(1))) uint32_t*)g,
        (__attribute__((address_space(3))) uint32_t*)l, 16, 0, 0);
}

template<int N>
DEV void waitcnt_vm() {
    if constexpr (N == 0)      asm volatile("s_waitcnt vmcnt(0)" ::: "memory");
    else if constexpr (N == 2) asm volatile("s_waitcnt vmcnt(2)" ::: "memory");
    else if constexpr (N == 3) asm volatile("s_waitcnt vmcnt(3)" ::: "memory");
    else if constexpr (N == 4) asm volatile("s_waitcnt vmcnt(4)" ::: "memory");
    else if constexpr (N == 6) asm volatile("s_waitcnt vmcnt(6)" ::: "memory");
    else static_assert(N == 0, "unsupported vmcnt");
}

// ---------------------------------------------------------------------------
// 1-pass bf16 MFMA GEMM.  A [M][K] bf16 (RNE), B [N][K] bf16 (RNE, k-major).
// C = A@B^T, fp32 accumulate.  3-buffer 2-DEEP prefetch pipeline with
// COUNTED vmcnt(TI4): tile t+2 issued before computing tile t; the barrier
// wait drains only tile t+1's loads (t+2 stays in flight) -> each load gets
// ~2 iterations to land instead of <1 (the R4..R10 1-deep drain).
// XCD-aware block swizzle; chunked LDS-bounce epilogue (coalesced stores).
// ---------------------------------------------------------------------------
template<int BM, int BN, bool BIAS, bool GELU, bool RES, bool POS,
         bool OUTF32, bool OUTB16>
__global__ __launch_bounds__(256)
void mfma_gemm(const uint16_t* __restrict__ Ah, const uint16_t* __restrict__ Bh,
               float* __restrict__ C, uint16_t* __restrict__ Cb,
               const float* __restrict__ bias, const float* __restrict__ res,
               const float* __restrict__ pos, int M, int N, int K)
{
    constexpr int WTM = BM / 2, WTN = BN / 2;
    constexpr int FM = WTM / 16, FN = WTN / 16;
    constexpr int NA = BM / 16, NB = BN / 16;      // 1KB chunks per plane
    constexpr int TI = NA + NB;                    // gloads per K-step
    constexpr int TI4 = TI / 4;                    // per wave
    constexpr int HALF = (BM + BN) * 64;           // bytes per K-step
    constexpr int BNP = BN + 4;
    constexpr int CR  = 32;                        // epilogue chunk rows
    constexpr int NCH = BM / CR;
    static_assert(CR * BNP * 4 <= 3 * HALF, "chunk must fit LDS");

    __shared__ __align__(16) uint8_t smem[3 * HALF];
    constexpr int offB = BM * 64;

    const int tid = threadIdx.x;
    const int w = tid >> 6, l = tid & 63;
    const int wr = w >> 1, wc = w & 1;

    // XCD-aware bijective swizzle (all grids here are %8 == 0)
    const int gx = gridDim.x;
    const int nwg = gx * gridDim.y;
    const int lin = blockIdx.y * gx + blockIdx.x;
    const int cpx = nwg >> 3;
    const int swz = (lin & 7) * cpx + (lin >> 3);
    const int bxs = swz % gx, bys = swz / gx;
    const int bm0 = bys * BM, bn0 = bxs * BN;
    const size_t sK = (size_t)K * 2;

    const int srow  = l >> 2;
    const int sslot = (l & 3) ^ ((l >> 3) & 3);
    const uint8_t* gsrc[TI4];
    uint32_t loff[TI4];
#pragma unroll
    for (int j = 0; j < TI4; ++j) {
        int f = w * TI4 + j;
        int p = (f < NA) ? 0 : 1;
        int c = p ? (f - NA) : f;
        const uint16_t* base = p ? Bh : Ah;
        int rb = p ? bn0 : bm0;
        gsrc[j] = (const uint8_t*)base + (size_t)(rb + c * 16 + srow) * sK + sslot * 16;
        loff[j] = (uint32_t)((p ? offB : 0) + c * 1024);
    }

    const int lr = l & 15;
    const int sl16 = ((l >> 4) ^ ((lr >> 1) & 3)) * 16;
    const int aofs = (wr * WTM + lr) * 64 + sl16;
    const int bofs = (wc * WTN + lr) * 64 + sl16;

    f32x4 acc[FM][FN];
#pragma unroll
    for (int m = 0; m < FM; ++m)
#pragma unroll
        for (int n = 0; n < FN; ++n) acc[m][n] = (f32x4){0.f, 0.f, 0.f, 0.f};

    const int NT = K >> 5;
    // ---- prologue: stage tiles 0 and 1; wait only for tile 0 ----
#pragma unroll
    for (int j = 0; j < TI4; ++j)
        gload16(gsrc[j], smem + loff[j]);
#pragma unroll
    for (int j = 0; j < TI4; ++j)
        gload16(gsrc[j] + 64, smem + HALF + loff[j]);
    waitcnt_vm<TI4>();
    __builtin_amdgcn_s_barrier();

    for (int t = 0; t < NT; ++t) {
        if (t + 2 < NT) {
            const size_t kb = (size_t)(t + 2) * 64;
            uint8_t* dst = smem + ((t + 2) % 3) * HALF;
#pragma unroll
            for (int j = 0; j < TI4; ++j)
                gload16(gsrc[j] + kb, dst + loff[j]);
        }
        const uint8_t* sb = smem + (t % 3) * HALF;
        s16x8 af[FM], bf[FN];
#pragma unroll
        for (int m = 0; m < FM; ++m)
            af[m] = *(const s16x8*)(sb + aofs + m * 1024);
#pragma unroll
        for (int n = 0; n < FN; ++n)
            bf[n] = *(const s16x8*)(sb + offB + bofs + n * 1024);
#pragma unroll
        for (int m = 0; m < FM; ++m)
#pragma unroll
            for (int n = 0; n < FN; ++n)
                acc[m][n] = __builtin_amdgcn_mfma_f32_16x16x32_bf16(af[m], bf[n], acc[m][n], 0, 0, 0);

        if (t + 2 < NT) {
            waitcnt_vm<TI4>();               // drain t+1 only; t+2 stays in flight
            __builtin_amdgcn_s_barrier();
        } else if (t + 1 < NT) {
            waitcnt_vm<0>();                 // nothing new issued; full drain
            __builtin_amdgcn_s_barrier();
        }
    }

    // ---- epilogue: chunked LDS bounce (CR rows/pass) ----
    float* lf = (float*)smem;
    const int r4 = (l >> 4) * 4;

    constexpr int C4PR = BN / 4;
    constexpr int RPP  = 256 / C4PR;
    const int rr = tid / C4PR, c4 = tid % C4PR;
    const int nn = bn0 + c4 * 4;

    float4 bv = {0.f, 0.f, 0.f, 0.f};
    if (BIAS) bv = *(const float4*)(bias + nn);

#pragma unroll
    for (int c = 0; c < NCH; ++c) {
        __syncthreads();   // prev chunk stores / K-loop reads done
        if (wr == (c * CR) / WTM) {
            const int mlo = ((c * CR) % WTM) / 16;
#pragma unroll
            for (int mi = 0; mi < CR / 16; ++mi) {
                int m = mlo + mi;
#pragma unroll
                for (int n = 0; n < FN; ++n) {
                    int col = wc * WTN + n * 16 + lr;
#pragma unroll
                    for (int r = 0; r < 4; ++r) {
                        int lrow = mi * 16 + r4 + r;
                        lf[lrow * BNP + col] = acc[m][n][r];
                    }
                }
            }
        }
        __syncthreads();
#pragma unroll
        for (int p = 0; p < CR / RPP; ++p) {
            int row = p * RPP + rr;
            int mm = bm0 + c * CR + row;
            float4 v = *(const float4*)&lf[row * BNP + c4 * 4];
            float* vp = &v.x;
            const float* bp = &bv.x;
#pragma unroll
            for (int q = 0; q < 4; ++q) {
                float x = vp[q];
                if (BIAS) x += bp[q];
                if (GELU) x = gelu_f(x);
                vp[q] = x;
            }
            if (RES) {
                float4 rv = *(const float4*)(res + (size_t)mm * N + nn);
                v.x += rv.x; v.y += rv.y; v.z += rv.z; v.w += rv.w;
            }
            if (POS) {
                float4 pv = *(const float4*)(pos + (size_t)(mm & 255) * N + nn);
                v.x += pv.x; v.y += pv.y; v.z += pv.z; v.w += pv.w;
            }
            size_t o = (size_t)mm * N + nn;
            if (OUTF32) *(float4*)(C + o) = v;
            if (OUTB16) {
                ushort4 hh;
                hh.x = bf16_rne(v.x); hh.y = bf16_rne(v.y);
                hh.z = bf16_rne(v.z); hh.w = bf16_rne(v.w);
                *(ushort4*)(Cb + o) = hh;
            }
        }
    }
}

// ---------------------------------------------------------------------------
// MFMA flash-style attention over RNE-bf16 QKV [8192][1536] u16.
// One block per (b,h); 4 waves x 64 queries.  Q held in REGISTERS.
// K/V staged in padded LDS.  LDS = 54 KB.  Softmax fp32, no max-subtraction.
// ---------------------------------------------------------------------------
__global__ __launch_bounds__(256)
void mfma_attn(const uint16_t* __restrict__ QKVb, uint16_t* __restrict__ Oh)
{
    __shared__ __align__(16) uint8_t lds[55296];
    uint8_t* Ks = lds;              // [64][144B]
    uint8_t* Vt = lds + 9216;       // [64][144B]   (rows = d, cols = k)
    uint8_t* Ps = lds + 18432;      // [256][144B]

    const int tid = threadIdx.x;
    const int w = tid >> 6, l = tid & 63;
    const int lr = l & 15, lg = l >> 4;
    const int bh = blockIdx.x;
    const int b = bh >> 3, h = bh & 7;
    const uint16_t* base = QKVb + (size_t)b * 256 * 1536 + h * 64;
    const int q0 = w * 64;

    // ---- Q fragments direct to registers (lane-private, reused all kt) ----
    s16x8 qreg[2][4];
#pragma unroll
    for (int ks = 0; ks < 2; ++ks)
#pragma unroll
        for (int m = 0; m < 4; ++m)
            qreg[ks][m] = *(const s16x8*)(base + (size_t)(q0 + m * 16 + lr) * 1536 + ks * 32 + lg * 8);

    f32x4 oacc[4][4];
    float lrun[4][4];
#pragma unroll
    for (int m = 0; m < 4; ++m)
#pragma unroll
        for (int n = 0; n < 4; ++n) { oacc[m][n] = (f32x4){0.f,0.f,0.f,0.f}; lrun[m][n] = 0.f; }

    for (int kt = 0; kt < 4; ++kt) {
        __syncthreads();   // prev tile reads done
        {
            int r = tid >> 2, sp = (tid & 3) * 2;
            const uint16_t* kp = base + (size_t)(kt * 64 + r) * 1536 + 512;
#pragma unroll
            for (int ss = 0; ss < 2; ++ss) {
                int s = sp + ss;
                *(s16x8*)(Ks + r * 144 + s * 16) = *(const s16x8*)(kp + s * 8);
            }
        }
        {
            int k = tid & 63, d0 = (tid >> 6) * 16;
            const uint16_t* vp = base + (size_t)(kt * 64 + k) * 1536 + 1024 + d0;
            s16x8 a = *(const s16x8*)(vp);
            s16x8 c = *(const s16x8*)(vp + 8);
#pragma unroll
            for (int i = 0; i < 8; ++i) {
                *(uint16_t*)(Vt + (d0 + i) * 144 + k * 2)     = (uint16_t)a[i];
                *(uint16_t*)(Vt + (d0 + 8 + i) * 144 + k * 2) = (uint16_t)c[i];
            }
        }
        __syncthreads();   // staging visible

        // ---- S = Q K^T ----
        f32x4 sacc[4][4];
#pragma unroll
        for (int m = 0; m < 4; ++m)
#pragma unroll
            for (int n = 0; n < 4; ++n) sacc[m][n] = (f32x4){0.f,0.f,0.f,0.f};
#pragma unroll
        for (int ks = 0; ks < 2; ++ks) {
            s16x8 kf[4];
#pragma unroll
            for (int n = 0; n < 4; ++n)
                kf[n] = *(const s16x8*)(Ks + (n * 16 + lr) * 144 + ks * 64 + lg * 16);
#pragma unroll
            for (int m = 0; m < 4; ++m)
#pragma unroll
                for (int n = 0; n < 4; ++n)
                    sacc[m][n] = __builtin_amdgcn_mfma_f32_16x16x32_bf16(qreg[ks][m], kf[n], sacc[m][n], 0, 0, 0);
        }

        // ---- exp + P write + denominator ----
        float dp[4][4];
#pragma unroll
        for (int m = 0; m < 4; ++m)
#pragma unroll
            for (int r = 0; r < 4; ++r) dp[m][r] = 0.f;
#pragma unroll
        for (int m = 0; m < 4; ++m) {
#pragma unroll
            for (int n = 0; n < 4; ++n) {
#pragma unroll
                for (int r = 0; r < 4; ++r) {
                    float e = __expf(sacc[m][n][r] * 0.125f);
                    dp[m][r] += e;
                    int q = q0 + m * 16 + lg * 4 + r;
                    int k = n * 16 + lr;
                    *(uint16_t*)(Ps + q * 144 + k * 2) = bf16_rne(e);
                }
            }
        }
#pragma unroll
        for (int m = 0; m < 4; ++m)
#pragma unroll
            for (int r = 0; r < 4; ++r) {
                float d = dp[m][r];
                d += __shfl_xor(d, 1);
                d += __shfl_xor(d, 2);
                d += __shfl_xor(d, 4);
                d += __shfl_xor(d, 8);
                lrun[m][r] += d;
            }

        asm volatile("s_waitcnt lgkmcnt(0)" ::: "memory");
        __builtin_amdgcn_sched_barrier(0);

        // ---- O += P V ----
#pragma unroll
        for (int ks = 0; ks < 2; ++ks) {
            s16x8 pf[4], vf[4];
#pragma unroll
            for (int m = 0; m < 4; ++m)
                pf[m] = *(const s16x8*)(Ps + (q0 + m * 16 + lr) * 144 + ks * 64 + lg * 16);
#pragma unroll
            for (int n = 0; n < 4; ++n)
                vf[n] = *(const s16x8*)(Vt + (n * 16 + lr) * 144 + ks * 64 + lg * 16);
#pragma unroll
            for (int m = 0; m < 4; ++m)
#pragma unroll
                for (int n = 0; n < 4; ++n)
                    oacc[m][n] = __builtin_amdgcn_mfma_f32_16x16x32_bf16(pf[m], vf[n], oacc[m][n], 0, 0, 0);
        }
    }

    // ---- normalize + chunked LDS bounce + coalesced store ----
    float inv[4][4];
#pragma unroll
    for (int m = 0; m < 4; ++m)
#pragma unroll
        for (int r = 0; r < 4; ++r) inv[m][r] = 1.f / lrun[m][r];

    float* OL = (float*)lds;       // [128][68 f32] per chunk = 34816 B
#pragma unroll
    for (int c = 0; c < 2; ++c) {
        __syncthreads();
        if ((w >> 1) == c) {
            const int lq0 = q0 - c * 128;
#pragma unroll
            for (int m = 0; m < 4; ++m)
#pragma unroll
                for (int n = 0; n < 4; ++n)
#pragma unroll
                    for (int r = 0; r < 4; ++r) {
                        int lq = lq0 + m * 16 + lg * 4 + r;
                        int d = n * 16 + lr;
                        OL[lq * 68 + d] = oacc[m][n][r] * inv[m][r];
                    }
        }
        __syncthreads();
#pragma unroll
        for (int p = 0; p < 8; ++p) {
            int lq = p * 16 + (tid >> 4);
            int q = c * 128 + lq;
            int d4 = tid & 15;
            f32x4 v = *(const f32x4*)(OL + lq * 68 + d4 * 4);
            ushort4 hh;
            hh.x = bf16_rne(v[0]); hh.y = bf16_rne(v[1]);
            hh.z = bf16_rne(v[2]); hh.w = bf16_rne(v[3]);
            size_t o = (size_t)(b * 256 + q) * 512 + h * 64 + d4 * 4;
            *(ushort4*)(Oh + o) = hh;
        }
    }
}

// ---------------------------------------------------------------------------
// Prep: images -> patch-gathered RNE bf16 [8192][3072]
// ---------------------------------------------------------------------------
__global__ __launch_bounds__(256)
void img2planes_kernel(const float* __restrict__ img, uint16_t* __restrict__ Ph)
{
    int idx = blockIdx.x * 256 + threadIdx.x;   // over 8192*768
    if (idx >= 8192 * 768) return;
    int m = idx / 768, q = idx - (idx / 768) * 768;
    int k = q * 4;
    int bb = m >> 8, n = m & 255;
    int ph = k / 96, rem = k - ph * 96;
    int prow = ((n >> 4) << 5) + ph;
    int pcol0 = (n & 15) << 5;
    const float* s = img + (((size_t)bb * 512 + prow) * 512 + pcol0) * 3 + rem;
    float4 v = *(const float4*)s;
    ushort4 hh;
    hh.x = bf16_rne(v.x); hh.y = bf16_rne(v.y);
    hh.z = bf16_rne(v.z); hh.w = bf16_rne(v.w);
    *(ushort4*)(Ph + (size_t)m * 3072 + k) = hh;
}

// two direct conversions in one dispatch (qkv_w + attn_out_w)
__global__ __launch_bounds__(256)
void conv_direct2_kernel(const float* __restrict__ s1, uint16_t* __restrict__ d1, int n1,
                         const float* __restrict__ s2, uint16_t* __restrict__ d2, int n2)
{
    int idx = blockIdx.x * 256 + threadIdx.x;
    const float* s; uint16_t* d; int i;
    if (idx < n1) { s = s1; d = d1; i = idx; }
    else if (idx < n1 + n2) { s = s2; d = d2; i = idx - n1; }
    else return;
    float4 v = *(const float4*)(s + (size_t)i * 4);
    ushort4 hh;
    hh.x = bf16_rne(v.x); hh.y = bf16_rne(v.y);
    hh.z = bf16_rne(v.z); hh.w = bf16_rne(v.w);
    *(ushort4*)(d + (size_t)i * 4) = hh;
}

__global__ __launch_bounds__(256)
void conv_transpose_kernel(const float* __restrict__ src, uint16_t* __restrict__ dh,
                           int K, int N)
{
    __shared__ float t[32][33];
    int k0 = blockIdx.x * 32, n0 = blockIdx.y * 32;
    const float* s = src + (size_t)blockIdx.z * K * N;
    size_t dbase = (size_t)blockIdx.z * N * K;
    int tid = threadIdx.x;
    {
        int kk = tid / 8, n4 = tid % 8;
        float4 v = *(const float4*)(s + (size_t)(k0 + kk) * N + n0 + n4 * 4);
        t[kk][n4 * 4 + 0] = v.x; t[kk][n4 * 4 + 1] = v.y;
        t[kk][n4 * 4 + 2] = v.z; t[kk][n4 * 4 + 3] = v.w;
    }
    __syncthreads();
    int nn = tid / 8, k4 = tid % 8;
    ushort4 hh;
    hh.x = bf16_rne(t[k4 * 4 + 0][nn]);
    hh.y = bf16_rne(t[k4 * 4 + 1][nn]);
    hh.z = bf16_rne(t[k4 * 4 + 2][nn]);
    hh.w = bf16_rne(t[k4 * 4 + 3][nn]);
    *(ushort4*)(dh + dbase + (size_t)(n0 + nn) * K + k0 + k4 * 4) = hh;
}

// ---------------------------------------------------------------------------
// LayerNorm over rows of 512; optionally emit RNE bf16.
// ---------------------------------------------------------------------------
template<bool PLANES>
__global__ __launch_bounds__(256)
void ln_kernel(const float* __restrict__ X, const float* __restrict__ g,
               const float* __restrict__ b, float* __restrict__ Y,
               uint16_t* __restrict__ Yh, int nrows)
{
    int wave = threadIdx.x >> 6;
    int lane = threadIdx.x & 63;
    int row = blockIdx.x * 4 + wave;
    if (row >= nrows) return;
    const float* x = X + (size_t)row * 512;
    float4 v0 = ((const float4*)x)[lane];
    float4 v1 = ((const float4*)x)[lane + 64];
    float s  = v0.x + v0.y + v0.z + v0.w + v1.x + v1.y + v1.z + v1.w;
    float sq = v0.x*v0.x + v0.y*v0.y + v0.z*v0.z + v0.w*v0.w
             + v1.x*v1.x + v1.y*v1.y + v1.z*v1.z + v1.w*v1.w;
#pragma unroll
    for (int off = 32; off > 0; off >>= 1) {
        s  += __shfl_down(s, off);
        sq += __shfl_down(sq, off);
    }
    s  = __shfl(s, 0);
    sq = __shfl(sq, 0);
    float mean = s * (1.f / 512.f);
    float var  = sq * (1.f / 512.f) - mean * mean;
    float rinv = rsqrtf(var + 1e-6f);
    float4 g0 = ((const float4*)g)[lane], g1 = ((const float4*)g)[lane + 64];
    float4 b0 = ((const float4*)b)[lane], b1 = ((const float4*)b)[lane + 64];
    float4 o0, o1;
    o0.x = (v0.x - mean) * rinv * g0.x + b0.x;
    o0.y = (v0.y - mean) * rinv * g0.y + b0.y;
    o0.z = (v0.z - mean) * rinv * g0.z + b0.z;
    o0.w = (v0.w - mean) * rinv * g0.w + b0.w;
    o1.x = (v1.x - mean) * rinv * g1.x + b1.x;
    o1.y = (v1.y - mean) * rinv * g1.y + b1.y;
    o1.z = (v1.z - mean) * rinv * g1.z + b1.z;
    o1.w = (v1.w - mean) * rinv * g1.w + b1.w;
    if (PLANES) {
        ushort4 hh0, hh1;
        hh0.x = bf16_rne(o0.x); hh0.y = bf16_rne(o0.y);
        hh0.z = bf16_rne(o0.z); hh0.w = bf16_rne(o0.w);
        hh1.x = bf16_rne(o1.x); hh1.y = bf16_rne(o1.y);
        hh1.z = bf16_rne(o1.z); hh1.w = bf16_rne(o1.w);
        size_t base = (size_t)row * 512;
        *(ushort4*)(Yh + base + lane * 4)       = hh0;
        *(ushort4*)(Yh + base + 256 + lane * 4) = hh1;
    } else {
        float* y = Y + (size_t)row * 512;
        ((float4*)y)[lane]      = o0;
        ((float4*)y)[lane + 64] = o1;
    }
}

// ---------------------------------------------------------------------------
// fp32 tiled GEMM (head layer 1 split-K)
// ---------------------------------------------------------------------------
template<int BM, int BN, int BK, int TM, int TN, bool SPLITK>
__global__ __launch_bounds__(256)
void gemm_kernel(const float* __restrict__ A, const float* __restrict__ B,
                 float* __restrict__ C, int M, int N, int K, int kchunk)
{
    constexpr int TX = BN / TN;
    constexpr int TY = BM / TM;
    static_assert(TX * TY == 256, "bad tile config");
    __shared__ float As[BK][BM + 4];
    __shared__ float Bs[BK][BN + 4];
    const int tid = threadIdx.x;
    const int tx  = tid % TX;
    const int ty  = tid / TX;
    const int bn0 = blockIdx.x * BN;
    const int bm0 = blockIdx.y * BM;
    int kstart = 0, kend = K;
    if (SPLITK) { kstart = blockIdx.z * kchunk; kend = kstart + kchunk; }
    float acc[TM][TN];
#pragma unroll
    for (int i = 0; i < TM; ++i)
#pragma unroll
        for (int j = 0; j < TN; ++j) acc[i][j] = 0.f;
    for (int k0 = kstart; k0 < kend; k0 += BK) {
        __syncthreads();
        constexpr int AV = BM * BK / 4 / 256;
#pragma unroll
        for (int r = 0; r < AV; ++r) {
            int idx = tid + r * 256;
            int k4 = idx % (BK / 4);
            int mm = idx / (BK / 4);
            float4 v = *(const float4*)(A + (size_t)(bm0 + mm) * K + k0 + k4 * 4);
            As[k4 * 4 + 0][mm] = v.x;
            As[k4 * 4 + 1][mm] = v.y;
            As[k4 * 4 + 2][mm] = v.z;
            As[k4 * 4 + 3][mm] = v.w;
        }
        constexpr int BV = BK * BN / 4 / 256;
#pragma unroll
        for (int r = 0; r < BV; ++r) {
            int idx = tid + r * 256;
            int n4 = idx % (BN / 4);
            int kk = idx / (BN / 4);
            float4 v = *(const float4*)(B + (size_t)(k0 + kk) * N + bn0 + n4 * 4);
            *(float4*)&Bs[kk][n4 * 4] = v;
        }
        __syncthreads();
#pragma unroll
        for (int kk = 0; kk < BK; ++kk) {
            float a[TM], b[TN];
#pragma unroll
            for (int i = 0; i < TM; i += 4)
                *(float4*)&a[i] = *(const float4*)&As[kk][ty * TM + i];
#pragma unroll
            for (int j = 0; j < TN; j += 4)
                *(float4*)&b[j] = *(const float4*)&Bs[kk][tx * TN + j];
#pragma unroll
            for (int i = 0; i < TM; ++i)
#pragma unroll
                for (int j = 0; j < TN; ++j)
                    acc[i][j] = fmaf(a[i], b[j], acc[i][j]);
        }
    }
    float* Cb = C;
    if (SPLITK) Cb += (size_t)blockIdx.z * M * N;
#pragma unroll
    for (int i = 0; i < TM; ++i) {
        int m = bm0 + ty * TM + i;
#pragma unroll
        for (int j = 0; j < TN; j += 4) {
            int n = bn0 + tx * TN + j;
            float4 v;
            v.x = acc[i][j + 0]; v.y = acc[i][j + 1];
            v.z = acc[i][j + 2]; v.w = acc[i][j + 3];
            *(float4*)(Cb + (size_t)m * N + n) = v;
        }
    }
}

__global__ __launch_bounds__(256)
void skinny_gemm_kernel(const float* __restrict__ A, const float* __restrict__ B,
                        float* __restrict__ P, int M, int N, int K, int kchunk)
{
    __shared__ float As[32][36];
    const int tid = threadIdx.x;
    const int tx  = tid & 63;
    const int ty  = tid >> 6;
    const int bn0 = blockIdx.x * 64;
    const int kstart = blockIdx.y * kchunk;
    const int kend   = kstart + kchunk;
    float acc[8];
#pragma unroll
    for (int i = 0; i < 8; ++i) acc[i] = 0.f;
    for (int k0 = kstart; k0 < kend; k0 += 32) {
        __syncthreads();
        {
            int row = tid >> 3;
            int k4  = tid & 7;
            float4 v = *(const float4*)(A + (size_t)row * K + k0 + k4 * 4);
            *(float4*)&As[row][k4 * 4] = v;
        }
        __syncthreads();
#pragma unroll 8
        for (int kk = 0; kk < 32; ++kk) {
            float b = B[(size_t)(k0 + kk) * N + bn0 + tx];
#pragma unroll
            for (int i = 0; i < 8; ++i)
                acc[i] = fmaf(As[ty * 8 + i][kk], b, acc[i]);
        }
    }
    float* Pb = P + (size_t)blockIdx.y * M * N;
#pragma unroll
    for (int i = 0; i < 8; ++i)
        Pb[(size_t)(ty * 8 + i) * N + bn0 + tx] = acc[i];
}

__global__ __launch_bounds__(256)
void reduce_gelu_kernel(const float* __restrict__ P, const float* __restrict__ bias,
                        float* __restrict__ Y, int total, int chunks, int N)
{
    int idx = blockIdx.x * 256 + threadIdx.x;
    if (idx >= total) return;
    float s = 0.f;
    for (int c = 0; c < chunks; ++c) s += P[(size_t)c * total + idx];
    s += bias[idx % N];
    Y[idx] = gelu_f(s);
}

// ---------------------------------------------------------------------------
// Fused head tail: F4 = gelu(F3 @ hW4 + hb4); F5 = gelu(F4 @ hW5 + hb5);
// out = F5 @ bbW + bbb.   One block, 256 threads, LDS staging between phases.
// ---------------------------------------------------------------------------
__global__ __launch_bounds__(256)
void head_tail_kernel(const float* __restrict__ F3, const float* __restrict__ hW4,
                      const float* __restrict__ hb4, const float* __restrict__ hW5,
                      const float* __restrict__ hb5, const float* __restrict__ bbW,
                      const float* __restrict__ bbb, float* __restrict__ out)
{
    __shared__ float F4s[32 * 64];
    __shared__ float F5s[32 * 32];
    const int tid = threadIdx.x;

    // phase 1: [32,512] @ [512,64] -> F4s (8 outputs/thread, fixed n)
    {
        const int n = tid & 63, mw = tid >> 6;   // mw in 0..3
        float acc[8];
#pragma unroll
        for (int i = 0; i < 8; ++i) acc[i] = 0.f;
        for (int k = 0; k < 512; ++k) {
            float wv = hW4[(size_t)k * 64 + n];
#pragma unroll
            for (int i = 0; i < 8; ++i)
                acc[i] = fmaf(F3[(size_t)(i * 4 + mw) * 512 + k], wv, acc[i]);
        }
#pragma unroll
        for (int i = 0; i < 8; ++i)
            F4s[(i * 4 + mw) * 64 + n] = gelu_f(acc[i] + hb4[n]);
    }
    __syncthreads();

    // phase 2: [32,64] @ [64,32] -> F5s (4 outputs/thread)
    {
        const int n = tid & 31, mw = tid >> 5;   // mw in 0..7
        float acc[4];
#pragma unroll
        for (int i = 0; i < 4; ++i) acc[i] = 0.f;
        for (int k = 0; k < 64; ++k) {
            float wv = hW5[(size_t)k * 32 + n];
#pragma unroll
            for (int i = 0; i < 4; ++i)
                acc[i] = fmaf(F4s[(i * 8 + mw) * 64 + k], wv, acc[i]);
        }
#pragma unroll
        for (int i = 0; i < 4; ++i)
            F5s[(i * 8 + mw) * 32 + n] = gelu_f(acc[i] + hb5[n]);
    }
    __syncthreads();

    // phase 3: [32,32] @ [32,4] -> out
    if (tid < 128) {
        int m = tid >> 2, n = tid & 3;
        float s = 0.f;
        for (int k = 0; k < 32; ++k)
            s = fmaf(F5s[m * 32 + k], bbW[(size_t)k * 4 + n], s);
        out[m * 4 + n] = s + bbb[n];
    }
}

// ---------------------------------------------------------------------------
extern "C" void kernel_launch(void* const* d_in, const int* in_sizes, int n_in,
                              void* d_out, int out_size, void* d_ws, size_t ws_size,
                              hipStream_t stream)
{
    const float* images     = (const float*)d_in[0];
    const float* W_proj     = (const float*)d_in[1];
    const float* b_proj     = (const float*)d_in[2];
    const float* pos_emb    = (const float*)d_in[3];
    const float* ln1_g      = (const float*)d_in[4];
    const float* ln1_b      = (const float*)d_in[5];
    const float* qkv_w      = (const float*)d_in[6];
    const float* qkv_b      = (const float*)d_in[7];
    const float* attn_out_w = (const float*)d_in[8];
    const float* attn_out_b = (const float*)d_in[9];
    const float* ln2_g      = (const float*)d_in[10];
    const float* ln2_b      = (const float*)d_in[11];
    const float* mlp_w1     = (const float*)d_in[12];
    const float* mlp_b1     = (const float*)d_in[13];
    const float* mlp_w2     = (const float*)d_in[14];
    const float* mlp_b2     = (const float*)d_in[15];
    const float* lnf_g      = (const float*)d_in[16];
    const float* lnf_b      = (const float*)d_in[17];
    const float* hW1 = (const float*)d_in[18];
    const float* hb1 = (const float*)d_in[19];
    const float* hW2 = (const float*)d_in[20];
    const float* hb2 = (const float*)d_in[21];
    const float* hW3 = (const float*)d_in[22];
    const float* hb3 = (const float*)d_in[23];
    const float* hW4 = (const float*)d_in[24];
    const float* hb4 = (const float*)d_in[25];
    const float* hW5 = (const float*)d_in[26];
    const float* hb5 = (const float*)d_in[27];
    const float* bbW = (const float*)d_in[28];
    const float* bbb = (const float*)d_in[29];

    // ---- workspace layout ----
    uint8_t* wsb = (uint8_t*)d_ws;
    size_t off = 0;
    auto alloc = [&](size_t bytes) { uint8_t* p = wsb + off; off += (bytes + 255) & ~(size_t)255; return p; };
    float*    X    = (float*)alloc(8192ull * 512 * 4);
    uint16_t* QKVb = (uint16_t*)alloc(8192ull * 1536 * 2);
    float*    T    = (float*)alloc(8192ull * 512 * 4);
    uint16_t* Xh   = (uint16_t*)alloc(8192ull * 512 * 2);
    uint16_t* Ohp  = (uint16_t*)alloc(8192ull * 512 * 2);
    uint16_t* Hh   = (uint16_t*)alloc(8192ull * 1024 * 2);
    uint16_t* Ph   = (uint16_t*)alloc(8192ull * 3072 * 2);
    uint16_t* WqH  = (uint16_t*)alloc(4ull * 1536 * 512 * 2);
    uint16_t* WaH  = (uint16_t*)alloc(4ull * 512 * 512 * 2);
    uint16_t* WpH  = (uint16_t*)alloc(512ull * 3072 * 2);
    uint16_t* W1H  = (uint16_t*)alloc(4ull * 1024 * 512 * 2);
    uint16_t* W2H  = (uint16_t*)alloc(4ull * 512 * 1024 * 2);
    float*    F1p  = (float*)alloc(128ull * 65536 * 4);
    float*    F1   = (float*)alloc(65536ull * 4);
    float*    P2   = (float*)alloc(64ull * 32768 * 4);
    float*    F2   = (float*)alloc(32768ull * 4);
    float*    P3   = (float*)alloc(32ull * 16384 * 4);
    float*    F3   = (float*)alloc(16384ull * 4);

    dim3 blk(256);

    // ---- prep: convert weights + images to RNE bf16 ----
    img2planes_kernel<<<(8192 * 768 + 255) / 256, blk, 0, stream>>>(images, Ph);
    conv_direct2_kernel<<<(1048576 + 255) / 256, blk, 0, stream>>>(
        qkv_w, WqH, 786432, attn_out_w, WaH, 262144);
    conv_transpose_kernel<<<dim3(3072 / 32, 512 / 32, 1), blk, 0, stream>>>(W_proj, WpH, 3072, 512);
    conv_transpose_kernel<<<dim3(512 / 32, 1024 / 32, 4), blk, 0, stream>>>(mlp_w1, W1H, 512, 1024);
    conv_transpose_kernel<<<dim3(1024 / 32, 512 / 32, 4), blk, 0, stream>>>(mlp_w2, W2H, 1024, 512);

    // ---- patch embed: X = patches @ W_proj + b_proj + pos   (64x128 tile) ----
    mfma_gemm<64, 128, true, false, false, true, true, false>
        <<<dim3(512 / 128, 8192 / 64), blk, 0, stream>>>(
            Ph, WpH, X, nullptr, b_proj, nullptr, pos_emb, 8192, 512, 3072);

    for (int l = 0; l < 4; ++l) {
        ln_kernel<true><<<2048, blk, 0, stream>>>(X, ln1_g + l * 512, ln1_b + l * 512,
                                                  nullptr, Xh, 8192);
        // qkv -> RNE bf16 (128^2 tile, grid 768)
        mfma_gemm<128, 128, true, false, false, false, false, true>
            <<<dim3(1536 / 128, 8192 / 128), blk, 0, stream>>>(
                Xh, WqH + (size_t)l * 1536 * 512, nullptr, QKVb,
                qkv_b + l * 1536, nullptr, nullptr, 8192, 1536, 512);
        mfma_attn<<<256, blk, 0, stream>>>(QKVb, Ohp);
        // attn_out (64x128 tile, grid 512)
        mfma_gemm<64, 128, true, false, true, false, true, false>
            <<<dim3(512 / 128, 8192 / 64), blk, 0, stream>>>(
                Ohp, WaH + (size_t)l * 512 * 512, X, nullptr,
                attn_out_b + l * 512, X, nullptr, 8192, 512, 512);
        ln_kernel<true><<<2048, blk, 0, stream>>>(X, ln2_g + l * 512, ln2_b + l * 512,
                                                  nullptr, Xh, 8192);
        // mlp1 (128^2 tile, grid 512)
        mfma_gemm<128, 128, true, true, false, false, false, true>
            <<<dim3(1024 / 128, 8192 / 128), blk, 0, stream>>>(
                Xh, W1H + (size_t)l * 1024 * 512, nullptr, Hh,
                mlp_b1 + l * 1024, nullptr, nullptr, 8192, 1024, 512);
        // mlp2 (64x128 tile, grid 512)
        mfma_gemm<64, 128, true, true, true, false, true, false>
            <<<dim3(512 / 128, 8192 / 64), blk, 0, stream>>>(
                Hh, W2H + (size_t)l * 512 * 1024, X, nullptr,
                mlp_b2 + l * 512, X, nullptr, 8192, 512, 1024);
    }

    // ---- final LN -> fp32 T ([32, 131072]) ----
    ln_kernel<false><<<2048, blk, 0, stream>>>(X, lnf_g, lnf_b, T, nullptr, 8192);

    // ---- MLP head ----
    gemm_kernel<32, 128, 32, 4, 4, true>
        <<<dim3(2048 / 128, 1, 128), blk, 0, stream>>>(
            T, hW1, F1p, 32, 2048, 131072, 131072 / 128);
    reduce_gelu_kernel<<<(65536 + 255) / 256, blk, 0, stream>>>(F1p, hb1, F1, 65536, 128, 2048);

    skinny_gemm_kernel<<<dim3(1024 / 64, 2048 / 32), blk, 0, stream>>>(F1, hW2, P2, 32, 1024, 2048, 32);
    reduce_gelu_kernel<<<(32768 + 255) / 256, blk, 0, stream>>>(P2, hb2, F2, 32768, 64, 1024);

    skinny_gemm_kernel<<<dim3(512 / 64, 1024 / 32), blk, 0, stream>>>(F2, hW3, P3, 32, 512, 1024, 32);
    reduce_gelu_kernel<<<(16384 + 255) / 256, blk, 0, stream>>>(P3, hb3, F3, 16384, 32, 512);

    // fused tail: h4 + h5 + bbox in one dispatch
    head_tail_kernel<<<1, blk, 0, stream>>>(F3, hW4, hb4, hW5, hb5, bbW, bbb, (float*)d_out);
}